// Round 1
// baseline (1910.417 us; speedup 1.0000x reference)
//
#include <hip/hip_runtime.h>

// Problem constants (fixed by the reference setup)
constexpr int N_NODES = 50000;
constexpr int G = 5;
constexpr int E = 850000;          // E0 (800000) + N self-loops
constexpr int GN = G * N_NODES;    // 250000
constexpr int GE = G * E;          // 4,250,000
constexpr float SLOPE = 0.2f;

static __device__ __forceinline__ float lrelu(float e) {
    return e > 0.f ? e : SLOPE * e;
}

// ---------------- GEMM1: h1[GN,64] = x[GN,128] @ W1[128,64] ----------------
__global__ __launch_bounds__(256) void k_gemm1(const float* __restrict__ x,
                                               const float* __restrict__ W1,
                                               float* __restrict__ h1) {
    __shared__ float Bs[128][68];   // W1 [k][col], pad->2-way max
    __shared__ float As[64][65];    // A^T chunk [k][row]
    const int t = threadIdx.x;
    const int rowBase = blockIdx.x * 64;

    // stage W1 fully: 8192 floats = 2048 float4, 8 per thread
    const float4* W14 = (const float4*)W1;
#pragma unroll
    for (int i = 0; i < 8; ++i) {
        int v = t + i * 256;
        int k = v >> 4;            // 16 float4 per 64-col row
        int c = (v & 15) << 2;
        float4 w = W14[v];
        Bs[k][c] = w.x; Bs[k][c + 1] = w.y; Bs[k][c + 2] = w.z; Bs[k][c + 3] = w.w;
    }

    const int tx = t & 15;         // col group (cols tx*4..+3)
    const int ty = t >> 4;         // row group (rows ty*4..+3)
    float acc[4][4] = {};
    const float4* x4 = (const float4*)x;

    for (int kc = 0; kc < 128; kc += 64) {
        __syncthreads();           // protect As reuse (also orders Bs stage on iter 0)
#pragma unroll
        for (int i = 0; i < 4; ++i) {
            int v = t + i * 256;   // 0..1023
            int r = v >> 4;        // 16 float4 per row chunk
            int kq = v & 15;
            int row = rowBase + r;
            float4 a = make_float4(0.f, 0.f, 0.f, 0.f);
            if (row < GN) a = x4[row * 32 + (kc >> 2) + kq];
            int kk = kq << 2;
            As[kk][r] = a.x; As[kk + 1][r] = a.y; As[kk + 2][r] = a.z; As[kk + 3][r] = a.w;
        }
        __syncthreads();
#pragma unroll 8
        for (int k = 0; k < 64; ++k) {
            float a0 = As[k][ty * 4 + 0];
            float a1 = As[k][ty * 4 + 1];
            float a2 = As[k][ty * 4 + 2];
            float a3 = As[k][ty * 4 + 3];
            float4 b = *(const float4*)&Bs[kc + k][tx * 4];
            acc[0][0] += a0 * b.x; acc[0][1] += a0 * b.y; acc[0][2] += a0 * b.z; acc[0][3] += a0 * b.w;
            acc[1][0] += a1 * b.x; acc[1][1] += a1 * b.y; acc[1][2] += a1 * b.z; acc[1][3] += a1 * b.w;
            acc[2][0] += a2 * b.x; acc[2][1] += a2 * b.y; acc[2][2] += a2 * b.z; acc[2][3] += a2 * b.w;
            acc[3][0] += a3 * b.x; acc[3][1] += a3 * b.y; acc[3][2] += a3 * b.z; acc[3][3] += a3 * b.w;
        }
    }
#pragma unroll
    for (int i = 0; i < 4; ++i) {
        int row = rowBase + ty * 4 + i;
        if (row < GN)
            ((float4*)h1)[row * 16 + tx] = make_float4(acc[i][0], acc[i][1], acc[i][2], acc[i][3]);
    }
}

// ---------- per-node attention coefficients, layer 1: [GN,8] each ----------
__global__ __launch_bounds__(256) void k_alphas1(const float* __restrict__ h1,
                                                 const float* __restrict__ a_src,
                                                 const float* __restrict__ a_dst,
                                                 float* __restrict__ as1,
                                                 float* __restrict__ ad1) {
    int idx = blockIdx.x * 256 + threadIdx.x;   // (n,h) flattened, GN*8
    if (idx >= GN * 8) return;
    int h = idx & 7;
    const float4* hv = (const float4*)h1 + idx * 2;   // h1 + idx*8 floats
    float4 v0 = hv[0], v1 = hv[1];
    const float4* s4 = (const float4*)a_src + h * 2;
    const float4* d4 = (const float4*)a_dst + h * 2;
    float4 s0 = s4[0], s1 = s4[1], t0 = d4[0], t1 = d4[1];
    as1[idx] = v0.x * s0.x + v0.y * s0.y + v0.z * s0.z + v0.w * s0.w
             + v1.x * s1.x + v1.y * s1.y + v1.z * s1.z + v1.w * s1.w;
    ad1[idx] = v0.x * t0.x + v0.y * t0.y + v0.z * t0.z + v0.w * t0.w
             + v1.x * t1.x + v1.y * t1.y + v1.z * t1.z + v1.w * t1.w;
}

// ---------------- edge pass 1, layer 1: denom[dst,h] += exp(e) -------------
__global__ __launch_bounds__(256) void k_den1(const int* __restrict__ ei,
                                              const float* __restrict__ as1,
                                              const float* __restrict__ ad1,
                                              float* __restrict__ den1) {
    int idx = blockIdx.x * 256 + threadIdx.x;   // (edge, h), GE*8 = 34M
    if (idx >= GE * 8) return;
    int h = idx & 7;
    int eid = idx >> 3;
    int g = eid / E;
    int el = eid - g * E;
    const int* base = ei + (size_t)g * 2 * E;
    int src = base[el];
    int dst = base[E + el];
    int no = g * N_NODES;
    float e = as1[(no + src) * 8 + h] + ad1[(no + dst) * 8 + h];
    atomicAdd(&den1[(no + dst) * 8 + h], __expf(lrelu(e)));
}

// ---- edge pass 2, layer 1: agg[dst,h,c] += alpha * h1[src,h,c] (t=h*8+c) ----
__global__ __launch_bounds__(256) void k_agg1(const int* __restrict__ ei,
                                              const float* __restrict__ as1,
                                              const float* __restrict__ ad1,
                                              const float* __restrict__ den1,
                                              const float* __restrict__ h1,
                                              float* __restrict__ agg1) {
    int idx = blockIdx.x * 256 + threadIdx.x;   // GE*64 = 272M
    if (idx >= GE * 64) return;
    int tt = idx & 63;
    int eid = idx >> 6;
    int h = tt >> 3;
    int g = eid / E;
    int el = eid - g * E;
    const int* base = ei + (size_t)g * 2 * E;
    int src = base[el];
    int dst = base[E + el];
    int no = g * N_NODES;
    int dh = (no + dst) * 8 + h;
    float e = lrelu(as1[(no + src) * 8 + h] + ad1[dh]);
    float alpha = __expf(e) / (den1[dh] + 1e-16f);
    atomicAdd(&agg1[((no + dst) << 6) + tt], alpha * h1[((no + src) << 6) + tt]);
}

// --------- GEMM2: h2[GN,16] = relu(agg1 + b1) @ W2[64,16] ------------------
__global__ __launch_bounds__(256) void k_gemm2(const float* __restrict__ agg1,
                                               const float* __restrict__ b1,
                                               const float* __restrict__ W2,
                                               float* __restrict__ h2) {
    __shared__ float As[64][65];   // [k][row], relu(agg1+b1)
    __shared__ float Bs[64][20];   // W2 [k][col]
    const int t = threadIdx.x;
    const int rowBase = blockIdx.x * 64;

    {   // stage W2: 1024 floats = 256 float4, exactly one per thread
        int k = t >> 2, c = (t & 3) << 2;
        float4 w = ((const float4*)W2)[t];
        Bs[k][c] = w.x; Bs[k][c + 1] = w.y; Bs[k][c + 2] = w.z; Bs[k][c + 3] = w.w;
    }
    const float4* a4p = (const float4*)agg1;
    const float4* b14 = (const float4*)b1;
#pragma unroll
    for (int i = 0; i < 4; ++i) {
        int v = t + i * 256;
        int r = v >> 4;
        int kq = v & 15;
        int row = rowBase + r;
        float4 a = make_float4(0.f, 0.f, 0.f, 0.f);
        if (row < GN) {
            a = a4p[row * 16 + kq];
            float4 bb = b14[kq];
            a.x = fmaxf(a.x + bb.x, 0.f);
            a.y = fmaxf(a.y + bb.y, 0.f);
            a.z = fmaxf(a.z + bb.z, 0.f);
            a.w = fmaxf(a.w + bb.w, 0.f);
        }
        int kk = kq << 2;
        As[kk][r] = a.x; As[kk + 1][r] = a.y; As[kk + 2][r] = a.z; As[kk + 3][r] = a.w;
    }
    __syncthreads();
    const int r = t >> 2;
    const int cg = (t & 3) << 2;
    float acc0 = 0.f, acc1 = 0.f, acc2 = 0.f, acc3 = 0.f;
#pragma unroll 8
    for (int k = 0; k < 64; ++k) {
        float a = As[k][r];
        float4 b = *(const float4*)&Bs[k][cg];
        acc0 += a * b.x; acc1 += a * b.y; acc2 += a * b.z; acc3 += a * b.w;
    }
    int row = rowBase + r;
    if (row < GN)
        ((float4*)h2)[row * 4 + (t & 3)] = make_float4(acc0, acc1, acc2, acc3);
}

// ---------- per-node attention coefficients, layer 2: [GN] each ------------
__global__ __launch_bounds__(256) void k_alphas2(const float* __restrict__ h2,
                                                 const float* __restrict__ a_src,
                                                 const float* __restrict__ a_dst,
                                                 float* __restrict__ as2,
                                                 float* __restrict__ ad2) {
    int idx = blockIdx.x * 256 + threadIdx.x;
    if (idx >= GN) return;
    const float4* hv = (const float4*)h2 + idx * 4;
    float s = 0.f, d = 0.f;
#pragma unroll
    for (int q = 0; q < 4; ++q) {
        float4 v = hv[q];
        float4 a = ((const float4*)a_src)[q];
        float4 b = ((const float4*)a_dst)[q];
        s += v.x * a.x + v.y * a.y + v.z * a.z + v.w * a.w;
        d += v.x * b.x + v.y * b.y + v.z * b.z + v.w * b.w;
    }
    as2[idx] = s;
    ad2[idx] = d;
}

// ---------------- edge pass 1, layer 2 -------------------------------------
__global__ __launch_bounds__(256) void k_den2(const int* __restrict__ ei,
                                              const float* __restrict__ as2,
                                              const float* __restrict__ ad2,
                                              float* __restrict__ den2) {
    int idx = blockIdx.x * 256 + threadIdx.x;   // GE
    if (idx >= GE) return;
    int g = idx / E;
    int el = idx - g * E;
    const int* base = ei + (size_t)g * 2 * E;
    int src = base[el];
    int dst = base[E + el];
    int no = g * N_NODES;
    float e = as2[no + src] + ad2[no + dst];
    atomicAdd(&den2[no + dst], __expf(lrelu(e)));
}

// ---------------- edge pass 2, layer 2 -------------------------------------
__global__ __launch_bounds__(256) void k_agg2(const int* __restrict__ ei,
                                              const float* __restrict__ as2,
                                              const float* __restrict__ ad2,
                                              const float* __restrict__ den2,
                                              const float* __restrict__ h2,
                                              float* __restrict__ agg2) {
    int idx = blockIdx.x * 256 + threadIdx.x;   // GE*16 = 68M
    if (idx >= GE * 16) return;
    int c = idx & 15;
    int eid = idx >> 4;
    int g = eid / E;
    int el = eid - g * E;
    const int* base = ei + (size_t)g * 2 * E;
    int src = base[el];
    int dst = base[E + el];
    int no = g * N_NODES;
    float e = lrelu(as2[no + src] + ad2[no + dst]);
    float alpha = __expf(e) / (den2[no + dst] + 1e-16f);
    atomicAdd(&agg2[((no + dst) << 4) + c], alpha * h2[((no + src) << 4) + c]);
}

// -------- final: out[n,2] = concat_g(agg2[g,n,:]+b2) @ Wf + bf -------------
__global__ __launch_bounds__(256) void k_final(const float* __restrict__ agg2,
                                               const float* __restrict__ b2,
                                               const float* __restrict__ Wf,
                                               const float* __restrict__ bf,
                                               float* __restrict__ out) {
    int n = blockIdx.x * 256 + threadIdx.x;
    if (n >= N_NODES) return;
    float o0 = bf[0], o1 = bf[1];
#pragma unroll
    for (int g = 0; g < G; ++g) {
        const float4* v4 = (const float4*)agg2 + (size_t)(g * N_NODES + n) * 4;
#pragma unroll
        for (int q = 0; q < 4; ++q) {
            float4 v = v4[q];
            float4 b = ((const float4*)b2)[q];
            v.x += b.x; v.y += b.y; v.z += b.z; v.w += b.w;
            int kb = g * 16 + q * 4;
            o0 += v.x * Wf[(kb + 0) * 2]     + v.y * Wf[(kb + 1) * 2]
                + v.z * Wf[(kb + 2) * 2]     + v.w * Wf[(kb + 3) * 2];
            o1 += v.x * Wf[(kb + 0) * 2 + 1] + v.y * Wf[(kb + 1) * 2 + 1]
                + v.z * Wf[(kb + 2) * 2 + 1] + v.w * Wf[(kb + 3) * 2 + 1];
        }
    }
    out[n * 2]     = o0;
    out[n * 2 + 1] = o1;
}

extern "C" void kernel_launch(void* const* d_in, const int* in_sizes, int n_in,
                              void* d_out, int out_size, void* d_ws, size_t ws_size,
                              hipStream_t stream) {
    const float* x      = (const float*)d_in[0];
    const int*   ei     = (const int*)d_in[1];
    const float* W1     = (const float*)d_in[2];
    const float* a_src1 = (const float*)d_in[3];
    const float* a_dst1 = (const float*)d_in[4];
    const float* b1     = (const float*)d_in[5];
    const float* W2     = (const float*)d_in[6];
    const float* a_src2 = (const float*)d_in[7];
    const float* a_dst2 = (const float*)d_in[8];
    const float* b2     = (const float*)d_in[9];
    const float* Wf     = (const float*)d_in[10];
    const float* bf     = (const float*)d_in[11];
    float* out = (float*)d_out;

    // workspace layout (fp32): 187 MB total
    float* ws   = (float*)d_ws;
    float* h1   = ws;                        // GN*64
    float* as1  = h1   + (size_t)GN * 64;    // GN*8
    float* ad1  = as1  + (size_t)GN * 8;     // GN*8
    float* den1 = ad1  + (size_t)GN * 8;     // GN*8
    float* agg1 = den1 + (size_t)GN * 8;     // GN*64
    float* h2   = agg1 + (size_t)GN * 64;    // GN*16
    float* as2  = h2   + (size_t)GN * 16;    // GN
    float* ad2  = as2  + GN;                 // GN
    float* den2 = ad2  + GN;                 // GN
    float* agg2 = den2 + GN;                 // GN*16

    hipMemsetAsync(den1, 0, (size_t)GN * 8 * sizeof(float), stream);
    hipMemsetAsync(agg1, 0, (size_t)GN * 64 * sizeof(float), stream);
    hipMemsetAsync(den2, 0, (size_t)GN * sizeof(float), stream);
    hipMemsetAsync(agg2, 0, (size_t)GN * 16 * sizeof(float), stream);

    k_gemm1  <<<(GN + 63) / 64, 256, 0, stream>>>(x, W1, h1);
    k_alphas1<<<(GN * 8 + 255) / 256, 256, 0, stream>>>(h1, a_src1, a_dst1, as1, ad1);
    k_den1   <<<(GE * 8 + 255) / 256, 256, 0, stream>>>(ei, as1, ad1, den1);
    k_agg1   <<<(GE * 64 + 255) / 256, 256, 0, stream>>>(ei, as1, ad1, den1, h1, agg1);
    k_gemm2  <<<(GN + 63) / 64, 256, 0, stream>>>(agg1, b1, W2, h2);
    k_alphas2<<<(GN + 255) / 256, 256, 0, stream>>>(h2, a_src2, a_dst2, as2, ad2);
    k_den2   <<<(GE + 255) / 256, 256, 0, stream>>>(ei, as2, ad2, den2);
    k_agg2   <<<(GE * 16 + 255) / 256, 256, 0, stream>>>(ei, as2, ad2, den2, h2, agg2);
    k_final  <<<(N_NODES + 255) / 256, 256, 0, stream>>>(agg2, b2, Wf, bf, out);
}

// Round 2
// 1155.822 us; speedup vs baseline: 1.6529x; 1.6529x over previous
//
#include <hip/hip_runtime.h>

// Problem constants (fixed by the reference setup)
constexpr int N_NODES = 50000;
constexpr int G = 5;
constexpr int E = 850000;          // E0 (800000) + N self-loops
constexpr int GN = G * N_NODES;    // 250000
constexpr int GE = G * E;          // 4,250,000
constexpr int NB = (GN + 1023) / 1024;  // 245 scan blocks
constexpr float SLOPE = 0.2f;

static __device__ __forceinline__ float lrelu(float e) {
    return e > 0.f ? e : SLOPE * e;
}

// ---------------- GEMM1: h1[GN,64] = x[GN,128] @ W1[128,64] ----------------
__global__ __launch_bounds__(256) void k_gemm1(const float* __restrict__ x,
                                               const float* __restrict__ W1,
                                               float* __restrict__ h1) {
    __shared__ float Bs[128][68];
    __shared__ float As[64][65];
    const int t = threadIdx.x;
    const int rowBase = blockIdx.x * 64;

    const float4* W14 = (const float4*)W1;
#pragma unroll
    for (int i = 0; i < 8; ++i) {
        int v = t + i * 256;
        int k = v >> 4;
        int c = (v & 15) << 2;
        float4 w = W14[v];
        Bs[k][c] = w.x; Bs[k][c + 1] = w.y; Bs[k][c + 2] = w.z; Bs[k][c + 3] = w.w;
    }

    const int tx = t & 15;
    const int ty = t >> 4;
    float acc[4][4] = {};
    const float4* x4 = (const float4*)x;

    for (int kc = 0; kc < 128; kc += 64) {
        __syncthreads();
#pragma unroll
        for (int i = 0; i < 4; ++i) {
            int v = t + i * 256;
            int r = v >> 4;
            int kq = v & 15;
            int row = rowBase + r;
            float4 a = make_float4(0.f, 0.f, 0.f, 0.f);
            if (row < GN) a = x4[row * 32 + (kc >> 2) + kq];
            int kk = kq << 2;
            As[kk][r] = a.x; As[kk + 1][r] = a.y; As[kk + 2][r] = a.z; As[kk + 3][r] = a.w;
        }
        __syncthreads();
#pragma unroll 8
        for (int k = 0; k < 64; ++k) {
            float a0 = As[k][ty * 4 + 0];
            float a1 = As[k][ty * 4 + 1];
            float a2 = As[k][ty * 4 + 2];
            float a3 = As[k][ty * 4 + 3];
            float4 b = *(const float4*)&Bs[kc + k][tx * 4];
            acc[0][0] += a0 * b.x; acc[0][1] += a0 * b.y; acc[0][2] += a0 * b.z; acc[0][3] += a0 * b.w;
            acc[1][0] += a1 * b.x; acc[1][1] += a1 * b.y; acc[1][2] += a1 * b.z; acc[1][3] += a1 * b.w;
            acc[2][0] += a2 * b.x; acc[2][1] += a2 * b.y; acc[2][2] += a2 * b.z; acc[2][3] += a2 * b.w;
            acc[3][0] += a3 * b.x; acc[3][1] += a3 * b.y; acc[3][2] += a3 * b.z; acc[3][3] += a3 * b.w;
        }
    }
#pragma unroll
    for (int i = 0; i < 4; ++i) {
        int row = rowBase + ty * 4 + i;
        if (row < GN)
            ((float4*)h1)[row * 16 + tx] = make_float4(acc[i][0], acc[i][1], acc[i][2], acc[i][3]);
    }
}

// ---------- per-node attention coefficients, layer 1: [GN,8] each ----------
__global__ __launch_bounds__(256) void k_alphas1(const float* __restrict__ h1,
                                                 const float* __restrict__ a_src,
                                                 const float* __restrict__ a_dst,
                                                 float* __restrict__ as1,
                                                 float* __restrict__ ad1) {
    int idx = blockIdx.x * 256 + threadIdx.x;
    if (idx >= GN * 8) return;
    int h = idx & 7;
    const float4* hv = (const float4*)h1 + idx * 2;
    float4 v0 = hv[0], v1 = hv[1];
    const float4* s4 = (const float4*)a_src + h * 2;
    const float4* d4 = (const float4*)a_dst + h * 2;
    float4 s0 = s4[0], s1 = s4[1], t0 = d4[0], t1 = d4[1];
    as1[idx] = v0.x * s0.x + v0.y * s0.y + v0.z * s0.z + v0.w * s0.w
             + v1.x * s1.x + v1.y * s1.y + v1.z * s1.z + v1.w * s1.w;
    ad1[idx] = v0.x * t0.x + v0.y * t0.y + v0.z * t0.z + v0.w * t0.w
             + v1.x * t1.x + v1.y * t1.y + v1.z * t1.z + v1.w * t1.w;
}

// ---------------- CSR build: count ----------------
__global__ __launch_bounds__(256) void k_count(const int* __restrict__ ei,
                                               int* __restrict__ deg) {
    int idx = blockIdx.x * 256 + threadIdx.x;
    if (idx >= GE) return;
    int g = idx / E;
    int el = idx - g * E;
    int dst = ei[(size_t)g * 2 * E + E + el];
    atomicAdd(&deg[g * N_NODES + dst], 1);
}

// ---------------- CSR build: scan (3 phases) ----------------
__global__ __launch_bounds__(256) void k_scan1(const int* __restrict__ deg,
                                               int* __restrict__ bsum) {
    __shared__ int s[256];
    int t = threadIdx.x, b = blockIdx.x;
    int base = b * 1024 + t * 4;
    int v = 0;
#pragma unroll
    for (int i = 0; i < 4; ++i) {
        int idx = base + i;
        if (idx < GN) v += deg[idx];
    }
    s[t] = v;
    __syncthreads();
    for (int off = 128; off > 0; off >>= 1) {
        if (t < off) s[t] += s[t + off];
        __syncthreads();
    }
    if (t == 0) bsum[b] = s[0];
}

__global__ __launch_bounds__(256) void k_scan2(const int* __restrict__ bsum,
                                               int* __restrict__ boff) {
    __shared__ int s[256];
    int t = threadIdx.x;
    int my = (t < NB) ? bsum[t] : 0;
    s[t] = my;
    for (int off = 1; off < 256; off <<= 1) {
        __syncthreads();
        int v = (t >= off) ? s[t - off] : 0;
        __syncthreads();
        s[t] += v;
    }
    if (t < NB) boff[t] = s[t] - my;   // exclusive
}

__global__ __launch_bounds__(256) void k_scan3(const int* __restrict__ deg,
                                               const int* __restrict__ boff,
                                               int* __restrict__ rowptr,
                                               int* __restrict__ cursor) {
    __shared__ int s[256];
    int t = threadIdx.x, b = blockIdx.x;
    int base = b * 1024 + t * 4;
    int d0 = 0, d1 = 0, d2 = 0, d3 = 0;
    if (base     < GN) d0 = deg[base];
    if (base + 1 < GN) d1 = deg[base + 1];
    if (base + 2 < GN) d2 = deg[base + 2];
    if (base + 3 < GN) d3 = deg[base + 3];
    int tsum = d0 + d1 + d2 + d3;
    s[t] = tsum;
    for (int off = 1; off < 256; off <<= 1) {
        __syncthreads();
        int v = (t >= off) ? s[t - off] : 0;
        __syncthreads();
        s[t] += v;
    }
    int excl = s[t] - tsum + boff[b];
    int p0 = excl, p1 = excl + d0, p2 = p1 + d1, p3 = p2 + d2;
    if (base     < GN) { rowptr[base]     = p0; cursor[base]     = p0; }
    if (base + 1 < GN) { rowptr[base + 1] = p1; cursor[base + 1] = p1; }
    if (base + 2 < GN) { rowptr[base + 2] = p2; cursor[base + 2] = p2; }
    if (base + 3 < GN) { rowptr[base + 3] = p3; cursor[base + 3] = p3; }
}

// ---------------- CSR build: fill ----------------
__global__ __launch_bounds__(256) void k_fill(const int* __restrict__ ei,
                                              int* __restrict__ cursor,
                                              int* __restrict__ csr) {
    int idx = blockIdx.x * 256 + threadIdx.x;
    if (idx >= GE) return;
    int g = idx / E;
    int el = idx - g * E;
    const int* base = ei + (size_t)g * 2 * E;
    int src = base[el];
    int dst = base[E + el];
    int pos = atomicAdd(&cursor[g * N_NODES + dst], 1);
    csr[pos] = g * N_NODES + src;   // global src id
}

// ------- layer-1 gather: per-dst softmax denom + aggregate, one wave/dst -------
__global__ __launch_bounds__(256) void k_layer1(const int* __restrict__ rowptr,
                                                const int* __restrict__ deg,
                                                const int* __restrict__ csr,
                                                const float* __restrict__ as1,
                                                const float* __restrict__ ad1,
                                                const float* __restrict__ h1,
                                                float* __restrict__ out1) {
    int d = blockIdx.x * 4 + (threadIdx.x >> 6);
    if (d >= GN) return;
    int tt = threadIdx.x & 63;          // h*8+c
    int h = tt >> 3;
    int start = rowptr[d];
    int dg = deg[d];
    float ad = ad1[d * 8 + h];
    float den = 0.f, acc = 0.f;
    int j = 0;
    for (; j + 2 <= dg; j += 2) {       // 2-wide for ILP (2 outstanding gathers)
        int s0 = csr[start + j];
        int s1 = csr[start + j + 1];
        float w0 = __expf(lrelu(as1[s0 * 8 + h] + ad));
        float w1 = __expf(lrelu(as1[s1 * 8 + h] + ad));
        float g0 = h1[s0 * 64 + tt];
        float g1 = h1[s1 * 64 + tt];
        den += w0 + w1;
        acc += w0 * g0 + w1 * g1;
    }
    if (j < dg) {
        int s0 = csr[start + j];
        float w0 = __expf(lrelu(as1[s0 * 8 + h] + ad));
        den += w0;
        acc += w0 * h1[s0 * 64 + tt];
    }
    out1[(size_t)d * 64 + tt] = acc / (den + 1e-16f);   // deg>=1 (self-loop)
}

// --------- GEMM2: h2[GN,16] = relu(out1 + b1) @ W2[64,16] ------------------
__global__ __launch_bounds__(256) void k_gemm2(const float* __restrict__ agg1,
                                               const float* __restrict__ b1,
                                               const float* __restrict__ W2,
                                               float* __restrict__ h2) {
    __shared__ float As[64][65];
    __shared__ float Bs[64][20];
    const int t = threadIdx.x;
    const int rowBase = blockIdx.x * 64;

    {
        int k = t >> 2, c = (t & 3) << 2;
        float4 w = ((const float4*)W2)[t];
        Bs[k][c] = w.x; Bs[k][c + 1] = w.y; Bs[k][c + 2] = w.z; Bs[k][c + 3] = w.w;
    }
    const float4* a4p = (const float4*)agg1;
    const float4* b14 = (const float4*)b1;
#pragma unroll
    for (int i = 0; i < 4; ++i) {
        int v = t + i * 256;
        int r = v >> 4;
        int kq = v & 15;
        int row = rowBase + r;
        float4 a = make_float4(0.f, 0.f, 0.f, 0.f);
        if (row < GN) {
            a = a4p[row * 16 + kq];
            float4 bb = b14[kq];
            a.x = fmaxf(a.x + bb.x, 0.f);
            a.y = fmaxf(a.y + bb.y, 0.f);
            a.z = fmaxf(a.z + bb.z, 0.f);
            a.w = fmaxf(a.w + bb.w, 0.f);
        }
        int kk = kq << 2;
        As[kk][r] = a.x; As[kk + 1][r] = a.y; As[kk + 2][r] = a.z; As[kk + 3][r] = a.w;
    }
    __syncthreads();
    const int r = t >> 2;
    const int cg = (t & 3) << 2;
    float acc0 = 0.f, acc1 = 0.f, acc2 = 0.f, acc3 = 0.f;
#pragma unroll 8
    for (int k = 0; k < 64; ++k) {
        float a = As[k][r];
        float4 b = *(const float4*)&Bs[k][cg];
        acc0 += a * b.x; acc1 += a * b.y; acc2 += a * b.z; acc3 += a * b.w;
    }
    int row = rowBase + r;
    if (row < GN)
        ((float4*)h2)[row * 4 + (t & 3)] = make_float4(acc0, acc1, acc2, acc3);
}

// ---------- per-node attention coefficients, layer 2 ------------
__global__ __launch_bounds__(256) void k_alphas2(const float* __restrict__ h2,
                                                 const float* __restrict__ a_src,
                                                 const float* __restrict__ a_dst,
                                                 float* __restrict__ as2,
                                                 float* __restrict__ ad2) {
    int idx = blockIdx.x * 256 + threadIdx.x;
    if (idx >= GN) return;
    const float4* hv = (const float4*)h2 + idx * 4;
    float s = 0.f, d = 0.f;
#pragma unroll
    for (int q = 0; q < 4; ++q) {
        float4 v = hv[q];
        float4 a = ((const float4*)a_src)[q];
        float4 b = ((const float4*)a_dst)[q];
        s += v.x * a.x + v.y * a.y + v.z * a.z + v.w * a.w;
        d += v.x * b.x + v.y * b.y + v.z * b.z + v.w * b.w;
    }
    as2[idx] = s;
    ad2[idx] = d;
}

// ------- layer-2 gather: one wave/dst, 16 ch x 4 edge-slots -------
__global__ __launch_bounds__(256) void k_layer2(const int* __restrict__ rowptr,
                                                const int* __restrict__ deg,
                                                const int* __restrict__ csr,
                                                const float* __restrict__ as2,
                                                const float* __restrict__ ad2,
                                                const float* __restrict__ h2,
                                                float* __restrict__ out2) {
    int d = blockIdx.x * 4 + (threadIdx.x >> 6);
    if (d >= GN) return;
    int tt = threadIdx.x & 63;
    int c = tt & 15;
    int sub = tt >> 4;                  // 4 edges per iteration
    int start = rowptr[d];
    int dg = deg[d];
    float ad = ad2[d];
    float den = 0.f, acc = 0.f;
    for (int base = 0; base < dg; base += 4) {
        int j = base + sub;
        bool val = j < dg;
        int s = val ? csr[start + j] : 0;
        float w = val ? __expf(lrelu(as2[s] + ad)) : 0.f;
        float g = val ? h2[s * 16 + c] : 0.f;
        den += w;
        acc += w * g;
    }
    acc += __shfl_xor(acc, 16); acc += __shfl_xor(acc, 32);
    den += __shfl_xor(den, 16); den += __shfl_xor(den, 32);
    if (sub == 0) out2[d * 16 + c] = acc / (den + 1e-16f);
}

// -------- final: out[n,2] = concat_g(out2[g,n,:]+b2) @ Wf + bf -------------
__global__ __launch_bounds__(256) void k_final(const float* __restrict__ agg2,
                                               const float* __restrict__ b2,
                                               const float* __restrict__ Wf,
                                               const float* __restrict__ bf,
                                               float* __restrict__ out) {
    int n = blockIdx.x * 256 + threadIdx.x;
    if (n >= N_NODES) return;
    float o0 = bf[0], o1 = bf[1];
#pragma unroll
    for (int g = 0; g < G; ++g) {
        const float4* v4 = (const float4*)agg2 + (size_t)(g * N_NODES + n) * 4;
#pragma unroll
        for (int q = 0; q < 4; ++q) {
            float4 v = v4[q];
            float4 b = ((const float4*)b2)[q];
            v.x += b.x; v.y += b.y; v.z += b.z; v.w += b.w;
            int kb = g * 16 + q * 4;
            o0 += v.x * Wf[(kb + 0) * 2]     + v.y * Wf[(kb + 1) * 2]
                + v.z * Wf[(kb + 2) * 2]     + v.w * Wf[(kb + 3) * 2];
            o1 += v.x * Wf[(kb + 0) * 2 + 1] + v.y * Wf[(kb + 1) * 2 + 1]
                + v.z * Wf[(kb + 2) * 2 + 1] + v.w * Wf[(kb + 3) * 2 + 1];
        }
    }
    out[n * 2]     = o0;
    out[n * 2 + 1] = o1;
}

extern "C" void kernel_launch(void* const* d_in, const int* in_sizes, int n_in,
                              void* d_out, int out_size, void* d_ws, size_t ws_size,
                              hipStream_t stream) {
    const float* x      = (const float*)d_in[0];
    const int*   ei     = (const int*)d_in[1];
    const float* W1     = (const float*)d_in[2];
    const float* a_src1 = (const float*)d_in[3];
    const float* a_dst1 = (const float*)d_in[4];
    const float* b1     = (const float*)d_in[5];
    const float* W2     = (const float*)d_in[6];
    const float* a_src2 = (const float*)d_in[7];
    const float* a_dst2 = (const float*)d_in[8];
    const float* b2     = (const float*)d_in[9];
    const float* Wf     = (const float*)d_in[10];
    const float* bf     = (const float*)d_in[11];
    float* out = (float*)d_out;

    // workspace layout with aliasing (lifetimes are disjoint):
    //   h1 [GN*64] ........ dead after k_layer1 -> out2 [GN*16] aliases it
    //   as1/ad1 [GN*8 ea] .. dead after k_layer1 -> h2 [GN*16] aliases them
    float* ws     = (float*)d_ws;
    float* h1     = ws;                          // GN*64 (16M floats)
    float* out2   = h1;                          // GN*16 alias (after h1 dead)
    float* as1    = h1   + (size_t)GN * 64;      // GN*8
    float* ad1    = as1  + (size_t)GN * 8;       // GN*8
    float* h2     = as1;                         // GN*16 alias (after as1/ad1 dead)
    float* out1   = ad1  + (size_t)GN * 8;       // GN*64 (16M floats)
    float* as2    = out1 + (size_t)GN * 64;      // GN
    float* ad2    = as2  + GN;                   // GN
    int*   deg    = (int*)(ad2 + GN);            // GN
    int*   rowptr = deg    + GN;                 // GN
    int*   cursor = rowptr + GN;                 // GN
    int*   csr    = cursor + GN;                 // GE
    int*   bsum   = csr    + GE;                 // NB
    int*   boff   = bsum   + NB;                 // NB

    hipMemsetAsync(deg, 0, (size_t)GN * sizeof(int), stream);

    // CSR build (shared by both layers) — overlaps nothing, cheap
    k_count<<<(GE + 255) / 256, 256, 0, stream>>>(ei, deg);
    k_scan1<<<NB, 256, 0, stream>>>(deg, bsum);
    k_scan2<<<1, 256, 0, stream>>>(bsum, boff);
    k_scan3<<<NB, 256, 0, stream>>>(deg, boff, rowptr, cursor);
    k_fill <<<(GE + 255) / 256, 256, 0, stream>>>(ei, cursor, csr);

    k_gemm1  <<<(GN + 63) / 64, 256, 0, stream>>>(x, W1, h1);
    k_alphas1<<<(GN * 8 + 255) / 256, 256, 0, stream>>>(h1, a_src1, a_dst1, as1, ad1);
    k_layer1 <<<(GN + 3) / 4, 256, 0, stream>>>(rowptr, deg, csr, as1, ad1, h1, out1);
    k_gemm2  <<<(GN + 63) / 64, 256, 0, stream>>>(out1, b1, W2, h2);
    k_alphas2<<<(GN + 255) / 256, 256, 0, stream>>>(h2, a_src2, a_dst2, as2, ad2);
    k_layer2 <<<(GN + 3) / 4, 256, 0, stream>>>(rowptr, deg, csr, as2, ad2, h2, out2);
    k_final  <<<(N_NODES + 255) / 256, 256, 0, stream>>>(out2, b2, Wf, bf, out);
}

// Round 3
// 828.703 us; speedup vs baseline: 2.3053x; 1.3947x over previous
//
#include <hip/hip_runtime.h>

// Problem constants (fixed by the reference setup)
constexpr int N_NODES = 50000;
constexpr int G = 5;
constexpr int E = 850000;            // E0 (800000) + N self-loops
constexpr int GN = G * N_NODES;      // 250000
constexpr int GE = G * E;            // 4,250,000
constexpr float SLOPE = 0.2f;

// Bucket sort parameters
constexpr int NPB = 1024;                        // nodes per bucket
constexpr int NBUK = (GN + NPB - 1) / NPB;       // 245
constexpr int EPB = 4096;                        // edges per block (256 thr x 16)
constexpr int NBLK_E = (GE + EPB - 1) / EPB;     // 1038

static __device__ __forceinline__ float lrelu(float e) {
    return e > 0.f ? e : SLOPE * e;
}

// ---------------- pass A1: per-block bucket histogram -----------------------
__global__ __launch_bounds__(256) void k_hist(const int* __restrict__ ei,
                                              int* __restrict__ H) {
    __shared__ int hist[NBUK];
    const int t = threadIdx.x, bi = blockIdx.x;
    for (int j = t; j < NBUK; j += 256) hist[j] = 0;
    __syncthreads();
#pragma unroll
    for (int i = 0; i < 16; ++i) {
        int idx = bi * EPB + i * 256 + t;
        if (idx < GE) {
            int g = idx / E;
            int el = idx - g * E;
            int dst = ei[(size_t)g * 2 * E + E + el];
            atomicAdd(&hist[(g * N_NODES + dst) >> 10], 1);
        }
    }
    __syncthreads();
    for (int j = t; j < NBUK; j += 256) H[(size_t)bi * NBUK + j] = hist[j];
}

// ------- pass A2a: per bucket, exclusive scan of H over blocks; totals ------
__global__ __launch_bounds__(256) void k_scanH(int* __restrict__ H,
                                               int* __restrict__ T) {
    __shared__ int s[256];
    const int t = threadIdx.x, b = blockIdx.x;
    int run = 0;
    for (int c = 0; c < NBLK_E; c += 256) {
        int bi = c + t;
        int v = (bi < NBLK_E) ? H[(size_t)bi * NBUK + b] : 0;
        s[t] = v;
        for (int off = 1; off < 256; off <<= 1) {
            __syncthreads();
            int u = (t >= off) ? s[t - off] : 0;
            __syncthreads();
            s[t] += u;
        }
        __syncthreads();
        int excl = s[t] - v;
        if (bi < NBLK_E) H[(size_t)bi * NBUK + b] = run + excl;
        run += s[255];
        __syncthreads();
    }
    if (t == 0) T[b] = run;
}

// ------- pass A2b: exclusive scan of bucket totals -> bucket bases ----------
__global__ __launch_bounds__(256) void k_scanT(const int* __restrict__ T,
                                               int* __restrict__ base_g) {
    __shared__ int s[256];
    const int t = threadIdx.x;
    int v = (t < NBUK) ? T[t] : 0;
    s[t] = v;
    for (int off = 1; off < 256; off <<= 1) {
        __syncthreads();
        int u = (t >= off) ? s[t - off] : 0;
        __syncthreads();
        s[t] += u;
    }
    __syncthreads();
    if (t < NBUK) base_g[t] = s[t] - v;
    if (t == 0) base_g[NBUK] = s[255];
}

// ------- pass A3: scatter packed (dstLow10<<18 | src) into bucket groups ----
__global__ __launch_bounds__(256) void k_scatter(const int* __restrict__ ei,
                                                 const int* __restrict__ H,
                                                 const int* __restrict__ base_g,
                                                 int* __restrict__ tmp) {
    __shared__ int cnt[NBUK];
    __shared__ int off[NBUK];
    const int t = threadIdx.x, bi = blockIdx.x;
    for (int j = t; j < NBUK; j += 256) {
        cnt[j] = 0;
        off[j] = base_g[j] + H[(size_t)bi * NBUK + j];
    }
    __syncthreads();
#pragma unroll
    for (int i = 0; i < 16; ++i) {
        int idx = bi * EPB + i * 256 + t;
        if (idx < GE) {
            int g = idx / E;
            int el = idx - g * E;
            const int* eb = ei + (size_t)g * 2 * E;
            int src = eb[el];
            int dst = eb[E + el];
            int gdst = g * N_NODES + dst;
            int b = gdst >> 10;
            int rank = atomicAdd(&cnt[b], 1);
            tmp[off[b] + rank] = ((gdst & 1023) << 18) | (g * N_NODES + src);
        }
    }
}

// ------- pass B: per-bucket LDS counting sort -> rowptr/deg/csr -------------
__global__ __launch_bounds__(256) void k_build(const int* __restrict__ base_g,
                                               const int* __restrict__ tmp,
                                               int* __restrict__ rowptr,
                                               int* __restrict__ deg,
                                               int* __restrict__ csr) {
    __shared__ int degL[NPB];
    __shared__ int curL[NPB];
    __shared__ int s[256];
    const int t = threadIdx.x, b = blockIdx.x;
    const int n0 = b << 10;
    const int nn = min(NPB, GN - n0);
    const int s0 = base_g[b], s1 = base_g[b + 1];
#pragma unroll
    for (int i = 0; i < 4; ++i) degL[t * 4 + i] = 0;
    __syncthreads();
    for (int i = s0 + t; i < s1; i += 256)
        atomicAdd(&degL[tmp[i] >> 18], 1);
    __syncthreads();
    // exclusive scan over 1024 (4 per thread)
    int j0 = t * 4;
    int d0 = degL[j0], d1 = degL[j0 + 1], d2 = degL[j0 + 2], d3 = degL[j0 + 3];
    int tsum = d0 + d1 + d2 + d3;
    s[t] = tsum;
    for (int off = 1; off < 256; off <<= 1) {
        __syncthreads();
        int u = (t >= off) ? s[t - off] : 0;
        __syncthreads();
        s[t] += u;
    }
    __syncthreads();
    int excl = s[t] - tsum;
    int p0 = excl, p1 = p0 + d0, p2 = p1 + d1, p3 = p2 + d2;
    curL[j0] = p0; curL[j0 + 1] = p1; curL[j0 + 2] = p2; curL[j0 + 3] = p3;
    if (j0     < nn) { rowptr[n0 + j0]     = s0 + p0; deg[n0 + j0]     = d0; }
    if (j0 + 1 < nn) { rowptr[n0 + j0 + 1] = s0 + p1; deg[n0 + j0 + 1] = d1; }
    if (j0 + 2 < nn) { rowptr[n0 + j0 + 2] = s0 + p2; deg[n0 + j0 + 2] = d2; }
    if (j0 + 3 < nn) { rowptr[n0 + j0 + 3] = s0 + p3; deg[n0 + j0 + 3] = d3; }
    __syncthreads();
    for (int i = s0 + t; i < s1; i += 256) {
        int e = tmp[i];
        int r = atomicAdd(&curL[e >> 18], 1);
        csr[s0 + r] = e & 0x3FFFF;
    }
}

// ---------------- GEMM1: h1ext[GN,72] (feats 0..63) = x @ W1 ----------------
__global__ __launch_bounds__(256) void k_gemm1(const float* __restrict__ x,
                                               const float* __restrict__ W1,
                                               float* __restrict__ h1ext) {
    __shared__ float Bs[128][68];
    __shared__ float As[64][65];
    const int t = threadIdx.x;
    const int rowBase = blockIdx.x * 64;

    const float4* W14 = (const float4*)W1;
#pragma unroll
    for (int i = 0; i < 8; ++i) {
        int v = t + i * 256;
        int k = v >> 4;
        int c = (v & 15) << 2;
        float4 w = W14[v];
        Bs[k][c] = w.x; Bs[k][c + 1] = w.y; Bs[k][c + 2] = w.z; Bs[k][c + 3] = w.w;
    }

    const int tx = t & 15;
    const int ty = t >> 4;
    float acc[4][4] = {};
    const float4* x4 = (const float4*)x;

    for (int kc = 0; kc < 128; kc += 64) {
        __syncthreads();
#pragma unroll
        for (int i = 0; i < 4; ++i) {
            int v = t + i * 256;
            int r = v >> 4;
            int kq = v & 15;
            int row = rowBase + r;
            float4 a = make_float4(0.f, 0.f, 0.f, 0.f);
            if (row < GN) a = x4[row * 32 + (kc >> 2) + kq];
            int kk = kq << 2;
            As[kk][r] = a.x; As[kk + 1][r] = a.y; As[kk + 2][r] = a.z; As[kk + 3][r] = a.w;
        }
        __syncthreads();
#pragma unroll 8
        for (int k = 0; k < 64; ++k) {
            float a0 = As[k][ty * 4 + 0];
            float a1 = As[k][ty * 4 + 1];
            float a2 = As[k][ty * 4 + 2];
            float a3 = As[k][ty * 4 + 3];
            float4 b = *(const float4*)&Bs[kc + k][tx * 4];
            acc[0][0] += a0 * b.x; acc[0][1] += a0 * b.y; acc[0][2] += a0 * b.z; acc[0][3] += a0 * b.w;
            acc[1][0] += a1 * b.x; acc[1][1] += a1 * b.y; acc[1][2] += a1 * b.z; acc[1][3] += a1 * b.w;
            acc[2][0] += a2 * b.x; acc[2][1] += a2 * b.y; acc[2][2] += a2 * b.z; acc[2][3] += a2 * b.w;
            acc[3][0] += a3 * b.x; acc[3][1] += a3 * b.y; acc[3][2] += a3 * b.z; acc[3][3] += a3 * b.w;
        }
    }
#pragma unroll
    for (int i = 0; i < 4; ++i) {
        int row = rowBase + ty * 4 + i;
        if (row < GN) {
            float4* dst = (float4*)(h1ext + (size_t)row * 72);
            dst[tx] = make_float4(acc[i][0], acc[i][1], acc[i][2], acc[i][3]);
        }
    }
}

// -- alphas1: weight logit -> h1ext[n][64+h]; dst logit -> ad1[n*8+h] --------
__global__ __launch_bounds__(256) void k_alphas1(float* __restrict__ h1ext,
                                                 const float* __restrict__ a_src,
                                                 const float* __restrict__ a_dst,
                                                 float* __restrict__ ad1) {
    int idx = blockIdx.x * 256 + threadIdx.x;   // (n,h), GN*8
    if (idx >= GN * 8) return;
    int h = idx & 7;
    int n = idx >> 3;
    const float4* hv = (const float4*)(h1ext + (size_t)n * 72) + h * 2;
    float4 v0 = hv[0], v1 = hv[1];
    const float4* s4 = (const float4*)a_src + h * 2;
    const float4* d4 = (const float4*)a_dst + h * 2;
    float4 s0 = s4[0], s1 = s4[1], t0 = d4[0], t1 = d4[1];
    h1ext[(size_t)n * 72 + 64 + h] =
          v0.x * s0.x + v0.y * s0.y + v0.z * s0.z + v0.w * s0.w
        + v1.x * s1.x + v1.y * s1.y + v1.z * s1.z + v1.w * s1.w;
    ad1[idx] = v0.x * t0.x + v0.y * t0.y + v0.z * t0.z + v0.w * t0.w
             + v1.x * t1.x + v1.y * t1.y + v1.z * t1.z + v1.w * t1.w;
}

// ------- layer-1 gather: per-dst softmax denom + aggregate, one wave/dst ----
__global__ __launch_bounds__(256) void k_layer1(const int* __restrict__ rowptr,
                                                const int* __restrict__ deg,
                                                const int* __restrict__ csr,
                                                const float* __restrict__ h1ext,
                                                const float* __restrict__ ad1,
                                                float* __restrict__ out1) {
    int d = blockIdx.x * 4 + (threadIdx.x >> 6);
    if (d >= GN) return;
    int tt = threadIdx.x & 63;          // h*8+c
    int h = tt >> 3;
    int start = rowptr[d];
    int dg = deg[d];
    float ad = ad1[d * 8 + h];
    float den = 0.f, acc = 0.f;
    int j = 0;
    for (; j + 2 <= dg; j += 2) {
        int s0 = csr[start + j];
        int s1 = csr[start + j + 1];
        const float* r0 = h1ext + (size_t)s0 * 72;
        const float* r1 = h1ext + (size_t)s1 * 72;
        float w0 = __expf(lrelu(r0[64 + h] + ad));
        float w1 = __expf(lrelu(r1[64 + h] + ad));
        float g0 = r0[tt];
        float g1 = r1[tt];
        den += w0 + w1;
        acc += w0 * g0 + w1 * g1;
    }
    if (j < dg) {
        int s0 = csr[start + j];
        const float* r0 = h1ext + (size_t)s0 * 72;
        float w0 = __expf(lrelu(r0[64 + h] + ad));
        den += w0;
        acc += w0 * r0[tt];
    }
    out1[(size_t)d * 64 + tt] = acc / (den + 1e-16f);
}

// --------- GEMM2: h2ext[GN,20] (0..15) = relu(out1 + b1) @ W2[64,16] --------
__global__ __launch_bounds__(256) void k_gemm2(const float* __restrict__ agg1,
                                               const float* __restrict__ b1,
                                               const float* __restrict__ W2,
                                               float* __restrict__ h2ext) {
    __shared__ float As[64][65];
    __shared__ float Bs[64][20];
    const int t = threadIdx.x;
    const int rowBase = blockIdx.x * 64;

    {
        int k = t >> 2, c = (t & 3) << 2;
        float4 w = ((const float4*)W2)[t];
        Bs[k][c] = w.x; Bs[k][c + 1] = w.y; Bs[k][c + 2] = w.z; Bs[k][c + 3] = w.w;
    }
    const float4* a4p = (const float4*)agg1;
    const float4* b14 = (const float4*)b1;
#pragma unroll
    for (int i = 0; i < 4; ++i) {
        int v = t + i * 256;
        int r = v >> 4;
        int kq = v & 15;
        int row = rowBase + r;
        float4 a = make_float4(0.f, 0.f, 0.f, 0.f);
        if (row < GN) {
            a = a4p[row * 16 + kq];
            float4 bb = b14[kq];
            a.x = fmaxf(a.x + bb.x, 0.f);
            a.y = fmaxf(a.y + bb.y, 0.f);
            a.z = fmaxf(a.z + bb.z, 0.f);
            a.w = fmaxf(a.w + bb.w, 0.f);
        }
        int kk = kq << 2;
        As[kk][r] = a.x; As[kk + 1][r] = a.y; As[kk + 2][r] = a.z; As[kk + 3][r] = a.w;
    }
    __syncthreads();
    const int r = t >> 2;
    const int cg = (t & 3) << 2;
    float acc0 = 0.f, acc1 = 0.f, acc2 = 0.f, acc3 = 0.f;
#pragma unroll 8
    for (int k = 0; k < 64; ++k) {
        float a = As[k][r];
        float4 b = *(const float4*)&Bs[k][cg];
        acc0 += a * b.x; acc1 += a * b.y; acc2 += a * b.z; acc3 += a * b.w;
    }
    int row = rowBase + r;
    if (row < GN) {
        float4* dst = (float4*)(h2ext + (size_t)row * 20);
        dst[t & 3] = make_float4(acc0, acc1, acc2, acc3);
    }
}

// ---- alphas2: weight logit -> h2ext[n][16]; dst logit -> ad2[n] ------------
__global__ __launch_bounds__(256) void k_alphas2(float* __restrict__ h2ext,
                                                 const float* __restrict__ a_src,
                                                 const float* __restrict__ a_dst,
                                                 float* __restrict__ ad2) {
    int idx = blockIdx.x * 256 + threadIdx.x;
    if (idx >= GN) return;
    const float4* hv = (const float4*)(h2ext + (size_t)idx * 20);
    float s = 0.f, d = 0.f;
#pragma unroll
    for (int q = 0; q < 4; ++q) {
        float4 v = hv[q];
        float4 a = ((const float4*)a_src)[q];
        float4 b = ((const float4*)a_dst)[q];
        s += v.x * a.x + v.y * a.y + v.z * a.z + v.w * a.w;
        d += v.x * b.x + v.y * b.y + v.z * b.z + v.w * b.w;
    }
    h2ext[(size_t)idx * 20 + 16] = s;
    ad2[idx] = d;
}

// ------- layer-2 gather: one wave/dst, 16 ch x 4 edge-slots -----------------
__global__ __launch_bounds__(256) void k_layer2(const int* __restrict__ rowptr,
                                                const int* __restrict__ deg,
                                                const int* __restrict__ csr,
                                                const float* __restrict__ h2ext,
                                                const float* __restrict__ ad2,
                                                float* __restrict__ out2) {
    int d = blockIdx.x * 4 + (threadIdx.x >> 6);
    if (d >= GN) return;
    int tt = threadIdx.x & 63;
    int c = tt & 15;
    int sub = tt >> 4;
    int start = rowptr[d];
    int dg = deg[d];
    float ad = ad2[d];
    float den = 0.f, acc = 0.f;
    for (int base = 0; base < dg; base += 4) {
        int j = base + sub;
        bool val = j < dg;
        int s = val ? csr[start + j] : 0;
        const float* r = h2ext + (size_t)s * 20;
        float w = val ? __expf(lrelu(r[16] + ad)) : 0.f;
        float g = val ? r[c] : 0.f;
        den += w;
        acc += w * g;
    }
    acc += __shfl_xor(acc, 16); acc += __shfl_xor(acc, 32);
    den += __shfl_xor(den, 16); den += __shfl_xor(den, 32);
    if (sub == 0) out2[(size_t)d * 16 + c] = acc / (den + 1e-16f);
}

// -------- final: out[n,2] = concat_g(out2[g,n,:]+b2) @ Wf + bf --------------
__global__ __launch_bounds__(256) void k_final(const float* __restrict__ agg2,
                                               const float* __restrict__ b2,
                                               const float* __restrict__ Wf,
                                               const float* __restrict__ bf,
                                               float* __restrict__ out) {
    int n = blockIdx.x * 256 + threadIdx.x;
    if (n >= N_NODES) return;
    float o0 = bf[0], o1 = bf[1];
#pragma unroll
    for (int g = 0; g < G; ++g) {
        const float4* v4 = (const float4*)agg2 + (size_t)(g * N_NODES + n) * 4;
#pragma unroll
        for (int q = 0; q < 4; ++q) {
            float4 v = v4[q];
            float4 b = ((const float4*)b2)[q];
            v.x += b.x; v.y += b.y; v.z += b.z; v.w += b.w;
            int kb = g * 16 + q * 4;
            o0 += v.x * Wf[(kb + 0) * 2]     + v.y * Wf[(kb + 1) * 2]
                + v.z * Wf[(kb + 2) * 2]     + v.w * Wf[(kb + 3) * 2];
            o1 += v.x * Wf[(kb + 0) * 2 + 1] + v.y * Wf[(kb + 1) * 2 + 1]
                + v.z * Wf[(kb + 2) * 2 + 1] + v.w * Wf[(kb + 3) * 2 + 1];
        }
    }
    out[n * 2]     = o0;
    out[n * 2 + 1] = o1;
}

extern "C" void kernel_launch(void* const* d_in, const int* in_sizes, int n_in,
                              void* d_out, int out_size, void* d_ws, size_t ws_size,
                              hipStream_t stream) {
    const float* x      = (const float*)d_in[0];
    const int*   ei     = (const int*)d_in[1];
    const float* W1     = (const float*)d_in[2];
    const float* a_src1 = (const float*)d_in[3];
    const float* a_dst1 = (const float*)d_in[4];
    const float* b1     = (const float*)d_in[5];
    const float* W2     = (const float*)d_in[6];
    const float* a_src2 = (const float*)d_in[7];
    const float* a_dst2 = (const float*)d_in[8];
    const float* b2     = (const float*)d_in[9];
    const float* Wf     = (const float*)d_in[10];
    const float* bf     = (const float*)d_in[11];
    float* out = (float*)d_out;

    // workspace (181 MB total, with lifetime aliasing):
    //   region A: h1ext[GN*72] (gemm1..layer1) -> h2ext[GN*20] + out2[GN*16]
    //   region B: out1[GN*64] (layer1..gemm2)
    //   region C: ad1[GN*8] (alphas1..layer1) -> ad2[GN]
    //   ints: rowptr, deg, base_g, T, H, tmp, csr
    float* fws   = (float*)d_ws;
    float* h1ext = fws;                                  // GN*72
    float* h2ext = fws;                                  // GN*20 (alias)
    float* out2  = fws + (size_t)GN * 20;                // GN*16 (alias)
    float* out1  = fws + (size_t)GN * 72;                // GN*64
    float* ad1   = out1 + (size_t)GN * 64;               // GN*8
    float* ad2   = ad1;                                  // GN (alias)
    int*   iws    = (int*)(ad1 + (size_t)GN * 8);
    int*   rowptr = iws;                                 // GN
    int*   deg    = rowptr + GN;                         // GN
    int*   base_g = deg + GN;                            // NBUK+1
    int*   T      = base_g + (NBUK + 1);                 // NBUK
    int*   H      = T + NBUK;                            // NBLK_E*NBUK
    int*   tmp    = H + (size_t)NBLK_E * NBUK;           // GE
    int*   csr    = tmp + GE;                            // GE

    // CSR build via bucket sort (no global atomics, coalesced writes)
    k_hist   <<<NBLK_E, 256, 0, stream>>>(ei, H);
    k_scanH  <<<NBUK,   256, 0, stream>>>(H, T);
    k_scanT  <<<1,      256, 0, stream>>>(T, base_g);
    k_scatter<<<NBLK_E, 256, 0, stream>>>(ei, H, base_g, tmp);
    k_build  <<<NBUK,   256, 0, stream>>>(base_g, tmp, rowptr, deg, csr);

    k_gemm1  <<<(GN + 63) / 64, 256, 0, stream>>>(x, W1, h1ext);
    k_alphas1<<<(GN * 8 + 255) / 256, 256, 0, stream>>>(h1ext, a_src1, a_dst1, ad1);
    k_layer1 <<<(GN + 3) / 4, 256, 0, stream>>>(rowptr, deg, csr, h1ext, ad1, out1);
    k_gemm2  <<<(GN + 63) / 64, 256, 0, stream>>>(out1, b1, W2, h2ext);
    k_alphas2<<<(GN + 255) / 256, 256, 0, stream>>>(h2ext, a_src2, a_dst2, ad2);
    k_layer2 <<<(GN + 3) / 4, 256, 0, stream>>>(rowptr, deg, csr, h2ext, ad2, out2);
    k_final  <<<(N_NODES + 255) / 256, 256, 0, stream>>>(out2, b2, Wf, bf, out);
}

// Round 4
// 705.766 us; speedup vs baseline: 2.7069x; 1.1742x over previous
//
#include <hip/hip_runtime.h>

// Problem constants (fixed by the reference setup)
constexpr int N_NODES = 50000;
constexpr int G = 5;
constexpr int E = 850000;            // E0 (800000) + N self-loops
constexpr int GN = G * N_NODES;      // 250000
constexpr int GE = G * E;            // 4,250,000
constexpr float SLOPE = 0.2f;

// Bucket sort parameters
constexpr int NPB = 1024;                        // nodes per bucket
constexpr int NBUK = (GN + NPB - 1) / NPB;       // 245
constexpr int EPB = 4096;                        // edges per block (256 thr x 16)
constexpr int NBLK_E = (GE + EPB - 1) / EPB;     // 1038

static __device__ __forceinline__ float lrelu(float e) {
    return e > 0.f ? e : SLOPE * e;
}
static __device__ __forceinline__ unsigned short f2h(float f) {
    union { _Float16 h; unsigned short u; } v;
    v.h = (_Float16)f;
    return v.u;
}
static __device__ __forceinline__ float h2f(unsigned short u) {
    union { unsigned short u; _Float16 h; } v;
    v.u = u;
    return (float)v.h;
}

// ---------------- pass A1: per-block bucket histogram -----------------------
__global__ __launch_bounds__(256) void k_hist(const int* __restrict__ ei,
                                              int* __restrict__ H) {
    __shared__ int hist[NBUK];
    const int t = threadIdx.x, bi = blockIdx.x;
    for (int j = t; j < NBUK; j += 256) hist[j] = 0;
    __syncthreads();
#pragma unroll
    for (int i = 0; i < 16; ++i) {
        int idx = bi * EPB + i * 256 + t;
        if (idx < GE) {
            int g = idx / E;
            int el = idx - g * E;
            int dst = ei[(size_t)g * 2 * E + E + el];
            atomicAdd(&hist[(g * N_NODES + dst) >> 10], 1);
        }
    }
    __syncthreads();
    for (int j = t; j < NBUK; j += 256) H[(size_t)bi * NBUK + j] = hist[j];
}

// ------- pass A2a: per bucket, exclusive scan of H over blocks; totals ------
__global__ __launch_bounds__(256) void k_scanH(int* __restrict__ H,
                                               int* __restrict__ T) {
    __shared__ int s[256];
    const int t = threadIdx.x, b = blockIdx.x;
    int run = 0;
    for (int c = 0; c < NBLK_E; c += 256) {
        int bi = c + t;
        int v = (bi < NBLK_E) ? H[(size_t)bi * NBUK + b] : 0;
        s[t] = v;
        for (int off = 1; off < 256; off <<= 1) {
            __syncthreads();
            int u = (t >= off) ? s[t - off] : 0;
            __syncthreads();
            s[t] += u;
        }
        __syncthreads();
        int excl = s[t] - v;
        if (bi < NBLK_E) H[(size_t)bi * NBUK + b] = run + excl;
        run += s[255];
        __syncthreads();
    }
    if (t == 0) T[b] = run;
}

// ------- pass A2b: exclusive scan of bucket totals -> bucket bases ----------
__global__ __launch_bounds__(256) void k_scanT(const int* __restrict__ T,
                                               int* __restrict__ base_g) {
    __shared__ int s[256];
    const int t = threadIdx.x;
    int v = (t < NBUK) ? T[t] : 0;
    s[t] = v;
    for (int off = 1; off < 256; off <<= 1) {
        __syncthreads();
        int u = (t >= off) ? s[t - off] : 0;
        __syncthreads();
        s[t] += u;
    }
    __syncthreads();
    if (t < NBUK) base_g[t] = s[t] - v;
    if (t == 0) base_g[NBUK] = s[255];
}

// ------- pass A3: scatter packed (dstLow10<<18 | src) into bucket groups ----
__global__ __launch_bounds__(256) void k_scatter(const int* __restrict__ ei,
                                                 const int* __restrict__ H,
                                                 const int* __restrict__ base_g,
                                                 int* __restrict__ tmp) {
    __shared__ int cnt[NBUK];
    __shared__ int off[NBUK];
    const int t = threadIdx.x, bi = blockIdx.x;
    for (int j = t; j < NBUK; j += 256) {
        cnt[j] = 0;
        off[j] = base_g[j] + H[(size_t)bi * NBUK + j];
    }
    __syncthreads();
#pragma unroll
    for (int i = 0; i < 16; ++i) {
        int idx = bi * EPB + i * 256 + t;
        if (idx < GE) {
            int g = idx / E;
            int el = idx - g * E;
            const int* eb = ei + (size_t)g * 2 * E;
            int src = eb[el];
            int dst = eb[E + el];
            int gdst = g * N_NODES + dst;
            int b = gdst >> 10;
            int rank = atomicAdd(&cnt[b], 1);
            tmp[off[b] + rank] = ((gdst & 1023) << 18) | (g * N_NODES + src);
        }
    }
}

// ------- pass B: per-bucket LDS counting sort -> rowptr/deg/csr -------------
__global__ __launch_bounds__(256) void k_build(const int* __restrict__ base_g,
                                               const int* __restrict__ tmp,
                                               int* __restrict__ rowptr,
                                               int* __restrict__ deg,
                                               int* __restrict__ csr) {
    __shared__ int degL[NPB];
    __shared__ int curL[NPB];
    __shared__ int s[256];
    const int t = threadIdx.x, b = blockIdx.x;
    const int n0 = b << 10;
    const int nn = min(NPB, GN - n0);
    const int s0 = base_g[b], s1 = base_g[b + 1];
#pragma unroll
    for (int i = 0; i < 4; ++i) degL[t * 4 + i] = 0;
    __syncthreads();
    for (int i = s0 + t; i < s1; i += 256)
        atomicAdd(&degL[tmp[i] >> 18], 1);
    __syncthreads();
    int j0 = t * 4;
    int d0 = degL[j0], d1 = degL[j0 + 1], d2 = degL[j0 + 2], d3 = degL[j0 + 3];
    int tsum = d0 + d1 + d2 + d3;
    s[t] = tsum;
    for (int off = 1; off < 256; off <<= 1) {
        __syncthreads();
        int u = (t >= off) ? s[t - off] : 0;
        __syncthreads();
        s[t] += u;
    }
    __syncthreads();
    int excl = s[t] - tsum;
    int p0 = excl, p1 = p0 + d0, p2 = p1 + d1, p3 = p2 + d2;
    curL[j0] = p0; curL[j0 + 1] = p1; curL[j0 + 2] = p2; curL[j0 + 3] = p3;
    if (j0     < nn) { rowptr[n0 + j0]     = s0 + p0; deg[n0 + j0]     = d0; }
    if (j0 + 1 < nn) { rowptr[n0 + j0 + 1] = s0 + p1; deg[n0 + j0 + 1] = d1; }
    if (j0 + 2 < nn) { rowptr[n0 + j0 + 2] = s0 + p2; deg[n0 + j0 + 2] = d2; }
    if (j0 + 3 < nn) { rowptr[n0 + j0 + 3] = s0 + p3; deg[n0 + j0 + 3] = d3; }
    __syncthreads();
    for (int i = s0 + t; i < s1; i += 256) {
        int e = tmp[i];
        int r = atomicAdd(&curL[e >> 18], 1);
        csr[s0 + r] = e & 0x3FFFF;
    }
}

// --- GEMM1 + fused logits: h1h[GN][72] fp16 (64 feats + 8 src-logits), ad1 fp32
__global__ __launch_bounds__(256) void k_gemm1(const float* __restrict__ x,
                                               const float* __restrict__ W1,
                                               const float* __restrict__ a_src,
                                               const float* __restrict__ a_dst,
                                               unsigned short* __restrict__ h1h,
                                               float* __restrict__ ad1) {
    __shared__ float Bs[128][68];
    __shared__ float As[64][65];
    __shared__ float aS[64], aD[64];
    const int t = threadIdx.x;
    const int rowBase = blockIdx.x * 64;

    const float4* W14 = (const float4*)W1;
#pragma unroll
    for (int i = 0; i < 8; ++i) {
        int v = t + i * 256;
        int k = v >> 4;
        int c = (v & 15) << 2;
        float4 w = W14[v];
        Bs[k][c] = w.x; Bs[k][c + 1] = w.y; Bs[k][c + 2] = w.z; Bs[k][c + 3] = w.w;
    }
    if (t < 64) { aS[t] = a_src[t]; aD[t] = a_dst[t]; }

    const int tx = t & 15;
    const int ty = t >> 4;
    float acc[4][4] = {};
    const float4* x4 = (const float4*)x;

    for (int kc = 0; kc < 128; kc += 64) {
        __syncthreads();
#pragma unroll
        for (int i = 0; i < 4; ++i) {
            int v = t + i * 256;
            int r = v >> 4;
            int kq = v & 15;
            int row = rowBase + r;
            float4 a = make_float4(0.f, 0.f, 0.f, 0.f);
            if (row < GN) a = x4[row * 32 + (kc >> 2) + kq];
            int kk = kq << 2;
            As[kk][r] = a.x; As[kk + 1][r] = a.y; As[kk + 2][r] = a.z; As[kk + 3][r] = a.w;
        }
        __syncthreads();
#pragma unroll 8
        for (int k = 0; k < 64; ++k) {
            float a0 = As[k][ty * 4 + 0];
            float a1 = As[k][ty * 4 + 1];
            float a2 = As[k][ty * 4 + 2];
            float a3 = As[k][ty * 4 + 3];
            float4 b = *(const float4*)&Bs[kc + k][tx * 4];
            acc[0][0] += a0 * b.x; acc[0][1] += a0 * b.y; acc[0][2] += a0 * b.z; acc[0][3] += a0 * b.w;
            acc[1][0] += a1 * b.x; acc[1][1] += a1 * b.y; acc[1][2] += a1 * b.z; acc[1][3] += a1 * b.w;
            acc[2][0] += a2 * b.x; acc[2][1] += a2 * b.y; acc[2][2] += a2 * b.z; acc[2][3] += a2 * b.w;
            acc[3][0] += a3 * b.x; acc[3][1] += a3 * b.y; acc[3][2] += a3 * b.z; acc[3][3] += a3 * b.w;
        }
    }
    const int head = tx >> 1;
    const int coff = (tx & 1) * 4;
#pragma unroll
    for (int i = 0; i < 4; ++i) {
        int row = rowBase + ty * 4 + i;
        float as_p = acc[i][0] * aS[head * 8 + coff]     + acc[i][1] * aS[head * 8 + coff + 1]
                   + acc[i][2] * aS[head * 8 + coff + 2] + acc[i][3] * aS[head * 8 + coff + 3];
        float ad_p = acc[i][0] * aD[head * 8 + coff]     + acc[i][1] * aD[head * 8 + coff + 1]
                   + acc[i][2] * aD[head * 8 + coff + 2] + acc[i][3] * aD[head * 8 + coff + 3];
        as_p += __shfl_xor(as_p, 1);
        ad_p += __shfl_xor(ad_p, 1);
        if (row < GN) {
            ushort4 fv = make_ushort4(f2h(acc[i][0]), f2h(acc[i][1]), f2h(acc[i][2]), f2h(acc[i][3]));
            *(ushort4*)(h1h + (size_t)row * 72 + tx * 4) = fv;
            if ((tx & 1) == 0) {
                h1h[(size_t)row * 72 + 64 + head] = f2h(as_p);
                ad1[row * 8 + head] = ad_p;
            }
        }
    }
}

// ------- layer-1 gather: per-dst softmax denom + aggregate, one wave/dst ----
__global__ __launch_bounds__(256) void k_layer1(const int* __restrict__ rowptr,
                                                const int* __restrict__ deg,
                                                const int* __restrict__ csr,
                                                const unsigned short* __restrict__ h1h,
                                                const float* __restrict__ ad1,
                                                float* __restrict__ out1) {
    int d = blockIdx.x * 4 + (threadIdx.x >> 6);
    if (d >= GN) return;
    int tt = threadIdx.x & 63;          // h*8+c
    int h = tt >> 3;
    int start = rowptr[d];
    int dg = deg[d];
    float ad = ad1[d * 8 + h];
    float den = 0.f, acc = 0.f;
    int j = 0;
    for (; j + 4 <= dg; j += 4) {       // 4-wide ILP (4 outstanding gathers)
        int s0 = csr[start + j];
        int s1 = csr[start + j + 1];
        int s2 = csr[start + j + 2];
        int s3 = csr[start + j + 3];
        const unsigned short* r0 = h1h + (size_t)s0 * 72;
        const unsigned short* r1 = h1h + (size_t)s1 * 72;
        const unsigned short* r2 = h1h + (size_t)s2 * 72;
        const unsigned short* r3 = h1h + (size_t)s3 * 72;
        float w0 = __expf(lrelu(h2f(r0[64 + h]) + ad));
        float w1 = __expf(lrelu(h2f(r1[64 + h]) + ad));
        float w2 = __expf(lrelu(h2f(r2[64 + h]) + ad));
        float w3 = __expf(lrelu(h2f(r3[64 + h]) + ad));
        float g0 = h2f(r0[tt]);
        float g1 = h2f(r1[tt]);
        float g2 = h2f(r2[tt]);
        float g3 = h2f(r3[tt]);
        den += (w0 + w1) + (w2 + w3);
        acc += w0 * g0 + w1 * g1 + w2 * g2 + w3 * g3;
    }
    for (; j + 2 <= dg; j += 2) {
        int s0 = csr[start + j];
        int s1 = csr[start + j + 1];
        const unsigned short* r0 = h1h + (size_t)s0 * 72;
        const unsigned short* r1 = h1h + (size_t)s1 * 72;
        float w0 = __expf(lrelu(h2f(r0[64 + h]) + ad));
        float w1 = __expf(lrelu(h2f(r1[64 + h]) + ad));
        float g0 = h2f(r0[tt]);
        float g1 = h2f(r1[tt]);
        den += w0 + w1;
        acc += w0 * g0 + w1 * g1;
    }
    if (j < dg) {
        int s0 = csr[start + j];
        const unsigned short* r0 = h1h + (size_t)s0 * 72;
        float w0 = __expf(lrelu(h2f(r0[64 + h]) + ad));
        den += w0;
        acc += w0 * h2f(r0[tt]);
    }
    out1[(size_t)d * 64 + tt] = acc / (den + 1e-16f);
}

// --- GEMM2 + fused logits: h2h[GN][24] fp16 (16 feats + logit), ad2 fp32 ----
__global__ __launch_bounds__(256) void k_gemm2(const float* __restrict__ agg1,
                                               const float* __restrict__ b1,
                                               const float* __restrict__ W2,
                                               const float* __restrict__ a_src,
                                               const float* __restrict__ a_dst,
                                               unsigned short* __restrict__ h2h,
                                               float* __restrict__ ad2) {
    __shared__ float As[64][65];
    __shared__ float Bs[64][20];
    __shared__ float aS[16], aD[16];
    const int t = threadIdx.x;
    const int rowBase = blockIdx.x * 64;

    {
        int k = t >> 2, c = (t & 3) << 2;
        float4 w = ((const float4*)W2)[t];
        Bs[k][c] = w.x; Bs[k][c + 1] = w.y; Bs[k][c + 2] = w.z; Bs[k][c + 3] = w.w;
    }
    if (t < 16) { aS[t] = a_src[t]; aD[t] = a_dst[t]; }
    const float4* a4p = (const float4*)agg1;
    const float4* b14 = (const float4*)b1;
#pragma unroll
    for (int i = 0; i < 4; ++i) {
        int v = t + i * 256;
        int r = v >> 4;
        int kq = v & 15;
        int row = rowBase + r;
        float4 a = make_float4(0.f, 0.f, 0.f, 0.f);
        if (row < GN) {
            a = a4p[row * 16 + kq];
            float4 bb = b14[kq];
            a.x = fmaxf(a.x + bb.x, 0.f);
            a.y = fmaxf(a.y + bb.y, 0.f);
            a.z = fmaxf(a.z + bb.z, 0.f);
            a.w = fmaxf(a.w + bb.w, 0.f);
        }
        int kk = kq << 2;
        As[kk][r] = a.x; As[kk + 1][r] = a.y; As[kk + 2][r] = a.z; As[kk + 3][r] = a.w;
    }
    __syncthreads();
    const int r = t >> 2;
    const int cg = (t & 3) << 2;
    float acc0 = 0.f, acc1 = 0.f, acc2 = 0.f, acc3 = 0.f;
#pragma unroll 8
    for (int k = 0; k < 64; ++k) {
        float a = As[k][r];
        float4 b = *(const float4*)&Bs[k][cg];
        acc0 += a * b.x; acc1 += a * b.y; acc2 += a * b.z; acc3 += a * b.w;
    }
    float as_p = acc0 * aS[cg] + acc1 * aS[cg + 1] + acc2 * aS[cg + 2] + acc3 * aS[cg + 3];
    float ad_p = acc0 * aD[cg] + acc1 * aD[cg + 1] + acc2 * aD[cg + 2] + acc3 * aD[cg + 3];
    as_p += __shfl_xor(as_p, 1); as_p += __shfl_xor(as_p, 2);
    ad_p += __shfl_xor(ad_p, 1); ad_p += __shfl_xor(ad_p, 2);
    int row = rowBase + r;
    if (row < GN) {
        ushort4 fv = make_ushort4(f2h(acc0), f2h(acc1), f2h(acc2), f2h(acc3));
        *(ushort4*)(h2h + (size_t)row * 24 + cg) = fv;
        if ((t & 3) == 0) {
            h2h[(size_t)row * 24 + 16] = f2h(as_p);
            ad2[row] = ad_p;
        }
    }
}

// ------- layer-2 gather: one wave/dst, 16 ch x 4 edge-slots -----------------
__global__ __launch_bounds__(256) void k_layer2(const int* __restrict__ rowptr,
                                                const int* __restrict__ deg,
                                                const int* __restrict__ csr,
                                                const unsigned short* __restrict__ h2h,
                                                const float* __restrict__ ad2,
                                                float* __restrict__ out2) {
    int d = blockIdx.x * 4 + (threadIdx.x >> 6);
    if (d >= GN) return;
    int tt = threadIdx.x & 63;
    int c = tt & 15;
    int sub = tt >> 4;
    int start = rowptr[d];
    int dg = deg[d];
    float ad = ad2[d];
    float den = 0.f, acc = 0.f;
    for (int base = 0; base < dg; base += 4) {
        int j = base + sub;
        bool val = j < dg;
        int s = val ? csr[start + j] : 0;
        const unsigned short* r = h2h + (size_t)s * 24;
        float w = val ? __expf(lrelu(h2f(r[16]) + ad)) : 0.f;
        float g = val ? h2f(r[c]) : 0.f;
        den += w;
        acc += w * g;
    }
    acc += __shfl_xor(acc, 16); acc += __shfl_xor(acc, 32);
    den += __shfl_xor(den, 16); den += __shfl_xor(den, 32);
    if (sub == 0) out2[(size_t)d * 16 + c] = acc / (den + 1e-16f);
}

// -------- final: out[n,2] = concat_g(out2[g,n,:]+b2) @ Wf + bf --------------
__global__ __launch_bounds__(256) void k_final(const float* __restrict__ agg2,
                                               const float* __restrict__ b2,
                                               const float* __restrict__ Wf,
                                               const float* __restrict__ bf,
                                               float* __restrict__ out) {
    int n = blockIdx.x * 256 + threadIdx.x;
    if (n >= N_NODES) return;
    float o0 = bf[0], o1 = bf[1];
#pragma unroll
    for (int g = 0; g < G; ++g) {
        const float4* v4 = (const float4*)agg2 + (size_t)(g * N_NODES + n) * 4;
#pragma unroll
        for (int q = 0; q < 4; ++q) {
            float4 v = v4[q];
            float4 b = ((const float4*)b2)[q];
            v.x += b.x; v.y += b.y; v.z += b.z; v.w += b.w;
            int kb = g * 16 + q * 4;
            o0 += v.x * Wf[(kb + 0) * 2]     + v.y * Wf[(kb + 1) * 2]
                + v.z * Wf[(kb + 2) * 2]     + v.w * Wf[(kb + 3) * 2];
            o1 += v.x * Wf[(kb + 0) * 2 + 1] + v.y * Wf[(kb + 1) * 2 + 1]
                + v.z * Wf[(kb + 2) * 2 + 1] + v.w * Wf[(kb + 3) * 2 + 1];
        }
    }
    out[n * 2]     = o0;
    out[n * 2 + 1] = o1;
}

extern "C" void kernel_launch(void* const* d_in, const int* in_sizes, int n_in,
                              void* d_out, int out_size, void* d_ws, size_t ws_size,
                              hipStream_t stream) {
    const float* x      = (const float*)d_in[0];
    const int*   ei     = (const int*)d_in[1];
    const float* W1     = (const float*)d_in[2];
    const float* a_src1 = (const float*)d_in[3];
    const float* a_dst1 = (const float*)d_in[4];
    const float* b1     = (const float*)d_in[5];
    const float* W2     = (const float*)d_in[6];
    const float* a_src2 = (const float*)d_in[7];
    const float* a_dst2 = (const float*)d_in[8];
    const float* b2     = (const float*)d_in[9];
    const float* Wf     = (const float*)d_in[10];
    const float* bf     = (const float*)d_in[11];
    float* out = (float*)d_out;

    // workspace layout (lifetime aliasing):
    //   region A (36 MB): h1h[GN*72 u16]  -> after layer1: h2h[GN*24 u16] + out2[GN*16 f32]
    //   region B (64 MB): out1[GN*64 f32]
    //   region C (8 MB):  ad1[GN*8 f32]   -> ad2[GN] alias
    //   ints: rowptr, deg, base_g, T, H, tmp, csr
    unsigned short* h1h = (unsigned short*)d_ws;             // GN*72 u16
    unsigned short* h2h = h1h;                               // GN*24 u16 (alias)
    float* out2 = (float*)(h1h + (size_t)GN * 24);           // GN*16 f32 (alias)
    float* out1 = (float*)(h1h + (size_t)GN * 72);           // GN*64 f32
    float* ad1  = out1 + (size_t)GN * 64;                    // GN*8 f32
    float* ad2  = ad1;                                       // GN (alias)
    int*   iws    = (int*)(ad1 + (size_t)GN * 8);
    int*   rowptr = iws;                                     // GN
    int*   deg    = rowptr + GN;                             // GN
    int*   base_g = deg + GN;                                // NBUK+1
    int*   T      = base_g + (NBUK + 1);                     // NBUK
    int*   H      = T + NBUK;                                // NBLK_E*NBUK
    int*   tmp    = H + (size_t)NBLK_E * NBUK;               // GE
    int*   csr    = tmp + GE;                                // GE

    // CSR build via bucket sort (no global atomics, coalesced writes)
    k_hist   <<<NBLK_E, 256, 0, stream>>>(ei, H);
    k_scanH  <<<NBUK,   256, 0, stream>>>(H, T);
    k_scanT  <<<1,      256, 0, stream>>>(T, base_g);
    k_scatter<<<NBLK_E, 256, 0, stream>>>(ei, H, base_g, tmp);
    k_build  <<<NBUK,   256, 0, stream>>>(base_g, tmp, rowptr, deg, csr);

    k_gemm1  <<<(GN + 63) / 64, 256, 0, stream>>>(x, W1, a_src1, a_dst1, h1h, ad1);
    k_layer1 <<<(GN + 3) / 4, 256, 0, stream>>>(rowptr, deg, csr, h1h, ad1, out1);
    k_gemm2  <<<(GN + 63) / 64, 256, 0, stream>>>(out1, b1, W2, a_src2, a_dst2, h2h, ad2);
    k_layer2 <<<(GN + 3) / 4, 256, 0, stream>>>(rowptr, deg, csr, h2h, ad2, out2);
    k_final  <<<(N_NODES + 255) / 256, 256, 0, stream>>>(out2, b2, Wf, bf, out);
}

// Round 5
// 634.747 us; speedup vs baseline: 3.0097x; 1.1119x over previous
//
#include <hip/hip_runtime.h>

// Problem constants (fixed by the reference setup)
constexpr int N_NODES = 50000;
constexpr int G = 5;
constexpr int E = 850000;            // E0 (800000) + N self-loops
constexpr int GN = G * N_NODES;      // 250000
constexpr int GE = G * E;            // 4,250,000
constexpr float SLOPE = 0.2f;

// Bucket sort parameters
constexpr int NPB = 1024;                        // nodes per bucket
constexpr int NBUK = (GN + NPB - 1) / NPB;       // 245
constexpr int EPB = 4096;                        // edges per block (256 thr x 16)
constexpr int NBLK_E = (GE + EPB - 1) / EPB;     // 1038

static __device__ __forceinline__ float lrelu(float e) {
    return e > 0.f ? e : SLOPE * e;
}
static __device__ __forceinline__ unsigned short f2h(float f) {
    union { _Float16 h; unsigned short u; } v;
    v.h = (_Float16)f;
    return v.u;
}
static __device__ __forceinline__ float h2f(unsigned short u) {
    union { unsigned short u; _Float16 h; } v;
    v.u = u;
    return (float)v.h;
}

// ---------------- pass A1: per-block bucket histogram -----------------------
__global__ __launch_bounds__(256) void k_hist(const int* __restrict__ ei,
                                              int* __restrict__ H) {
    __shared__ int hist[NBUK];
    const int t = threadIdx.x, bi = blockIdx.x;
    for (int j = t; j < NBUK; j += 256) hist[j] = 0;
    __syncthreads();
#pragma unroll
    for (int i = 0; i < 16; ++i) {
        int idx = bi * EPB + i * 256 + t;
        if (idx < GE) {
            int g = idx / E;
            int el = idx - g * E;
            int dst = ei[(size_t)g * 2 * E + E + el];
            atomicAdd(&hist[(g * N_NODES + dst) >> 10], 1);
        }
    }
    __syncthreads();
    for (int j = t; j < NBUK; j += 256) H[(size_t)bi * NBUK + j] = hist[j];
}

// ------- pass A2a: per bucket, exclusive scan of H over blocks; totals ------
__global__ __launch_bounds__(256) void k_scanH(int* __restrict__ H,
                                               int* __restrict__ T) {
    __shared__ int s[256];
    const int t = threadIdx.x, b = blockIdx.x;
    int run = 0;
    for (int c = 0; c < NBLK_E; c += 256) {
        int bi = c + t;
        int v = (bi < NBLK_E) ? H[(size_t)bi * NBUK + b] : 0;
        s[t] = v;
        for (int off = 1; off < 256; off <<= 1) {
            __syncthreads();
            int u = (t >= off) ? s[t - off] : 0;
            __syncthreads();
            s[t] += u;
        }
        __syncthreads();
        int excl = s[t] - v;
        if (bi < NBLK_E) H[(size_t)bi * NBUK + b] = run + excl;
        run += s[255];
        __syncthreads();
    }
    if (t == 0) T[b] = run;
}

// ------- pass A2b: exclusive scan of bucket totals -> bucket bases ----------
__global__ __launch_bounds__(256) void k_scanT(const int* __restrict__ T,
                                               int* __restrict__ base_g) {
    __shared__ int s[256];
    const int t = threadIdx.x;
    int v = (t < NBUK) ? T[t] : 0;
    s[t] = v;
    for (int off = 1; off < 256; off <<= 1) {
        __syncthreads();
        int u = (t >= off) ? s[t - off] : 0;
        __syncthreads();
        s[t] += u;
    }
    __syncthreads();
    if (t < NBUK) base_g[t] = s[t] - v;
    if (t == 0) base_g[NBUK] = s[255];
}

// ------- pass A3: scatter packed (dstLow10<<18 | src) into bucket groups ----
__global__ __launch_bounds__(256) void k_scatter(const int* __restrict__ ei,
                                                 const int* __restrict__ H,
                                                 const int* __restrict__ base_g,
                                                 int* __restrict__ tmp) {
    __shared__ int cnt[NBUK];
    __shared__ int off[NBUK];
    const int t = threadIdx.x, bi = blockIdx.x;
    for (int j = t; j < NBUK; j += 256) {
        cnt[j] = 0;
        off[j] = base_g[j] + H[(size_t)bi * NBUK + j];
    }
    __syncthreads();
#pragma unroll
    for (int i = 0; i < 16; ++i) {
        int idx = bi * EPB + i * 256 + t;
        if (idx < GE) {
            int g = idx / E;
            int el = idx - g * E;
            const int* eb = ei + (size_t)g * 2 * E;
            int src = eb[el];
            int dst = eb[E + el];
            int gdst = g * N_NODES + dst;
            int b = gdst >> 10;
            int rank = atomicAdd(&cnt[b], 1);
            tmp[off[b] + rank] = ((gdst & 1023) << 18) | (g * N_NODES + src);
        }
    }
}

// ------- pass B: per-bucket LDS counting sort -> rowptr/deg/csr -------------
__global__ __launch_bounds__(256) void k_build(const int* __restrict__ base_g,
                                               const int* __restrict__ tmp,
                                               int* __restrict__ rowptr,
                                               int* __restrict__ deg,
                                               int* __restrict__ csr) {
    __shared__ int degL[NPB];
    __shared__ int curL[NPB];
    __shared__ int s[256];
    const int t = threadIdx.x, b = blockIdx.x;
    const int n0 = b << 10;
    const int nn = min(NPB, GN - n0);
    const int s0 = base_g[b], s1 = base_g[b + 1];
#pragma unroll
    for (int i = 0; i < 4; ++i) degL[t * 4 + i] = 0;
    __syncthreads();
    for (int i = s0 + t; i < s1; i += 256)
        atomicAdd(&degL[tmp[i] >> 18], 1);
    __syncthreads();
    int j0 = t * 4;
    int d0 = degL[j0], d1 = degL[j0 + 1], d2 = degL[j0 + 2], d3 = degL[j0 + 3];
    int tsum = d0 + d1 + d2 + d3;
    s[t] = tsum;
    for (int off = 1; off < 256; off <<= 1) {
        __syncthreads();
        int u = (t >= off) ? s[t - off] : 0;
        __syncthreads();
        s[t] += u;
    }
    __syncthreads();
    int excl = s[t] - tsum;
    int p0 = excl, p1 = p0 + d0, p2 = p1 + d1, p3 = p2 + d2;
    curL[j0] = p0; curL[j0 + 1] = p1; curL[j0 + 2] = p2; curL[j0 + 3] = p3;
    if (j0     < nn) { rowptr[n0 + j0]     = s0 + p0; deg[n0 + j0]     = d0; }
    if (j0 + 1 < nn) { rowptr[n0 + j0 + 1] = s0 + p1; deg[n0 + j0 + 1] = d1; }
    if (j0 + 2 < nn) { rowptr[n0 + j0 + 2] = s0 + p2; deg[n0 + j0 + 2] = d2; }
    if (j0 + 3 < nn) { rowptr[n0 + j0 + 3] = s0 + p3; deg[n0 + j0 + 3] = d3; }
    __syncthreads();
    for (int i = s0 + t; i < s1; i += 256) {
        int e = tmp[i];
        int r = atomicAdd(&curL[e >> 18], 1);
        csr[s0 + r] = e & 0x3FFFF;
    }
}

// --- GEMM1 + fused logits: h1f[GN][64] fp16 (128B rows), l1[GN][8] fp16,
//     ad1[GN][8] fp32
__global__ __launch_bounds__(256) void k_gemm1(const float* __restrict__ x,
                                               const float* __restrict__ W1,
                                               const float* __restrict__ a_src,
                                               const float* __restrict__ a_dst,
                                               unsigned short* __restrict__ h1f,
                                               unsigned short* __restrict__ l1,
                                               float* __restrict__ ad1) {
    __shared__ float Bs[128][68];
    __shared__ float As[64][65];
    __shared__ float aS[64], aD[64];
    const int t = threadIdx.x;
    const int rowBase = blockIdx.x * 64;

    const float4* W14 = (const float4*)W1;
#pragma unroll
    for (int i = 0; i < 8; ++i) {
        int v = t + i * 256;
        int k = v >> 4;
        int c = (v & 15) << 2;
        float4 w = W14[v];
        Bs[k][c] = w.x; Bs[k][c + 1] = w.y; Bs[k][c + 2] = w.z; Bs[k][c + 3] = w.w;
    }
    if (t < 64) { aS[t] = a_src[t]; aD[t] = a_dst[t]; }

    const int tx = t & 15;
    const int ty = t >> 4;
    float acc[4][4] = {};
    const float4* x4 = (const float4*)x;

    for (int kc = 0; kc < 128; kc += 64) {
        __syncthreads();
#pragma unroll
        for (int i = 0; i < 4; ++i) {
            int v = t + i * 256;
            int r = v >> 4;
            int kq = v & 15;
            int row = rowBase + r;
            float4 a = make_float4(0.f, 0.f, 0.f, 0.f);
            if (row < GN) a = x4[row * 32 + (kc >> 2) + kq];
            int kk = kq << 2;
            As[kk][r] = a.x; As[kk + 1][r] = a.y; As[kk + 2][r] = a.z; As[kk + 3][r] = a.w;
        }
        __syncthreads();
#pragma unroll 8
        for (int k = 0; k < 64; ++k) {
            float a0 = As[k][ty * 4 + 0];
            float a1 = As[k][ty * 4 + 1];
            float a2 = As[k][ty * 4 + 2];
            float a3 = As[k][ty * 4 + 3];
            float4 b = *(const float4*)&Bs[kc + k][tx * 4];
            acc[0][0] += a0 * b.x; acc[0][1] += a0 * b.y; acc[0][2] += a0 * b.z; acc[0][3] += a0 * b.w;
            acc[1][0] += a1 * b.x; acc[1][1] += a1 * b.y; acc[1][2] += a1 * b.z; acc[1][3] += a1 * b.w;
            acc[2][0] += a2 * b.x; acc[2][1] += a2 * b.y; acc[2][2] += a2 * b.z; acc[2][3] += a2 * b.w;
            acc[3][0] += a3 * b.x; acc[3][1] += a3 * b.y; acc[3][2] += a3 * b.z; acc[3][3] += a3 * b.w;
        }
    }
    const int head = tx >> 1;
    const int coff = (tx & 1) * 4;
#pragma unroll
    for (int i = 0; i < 4; ++i) {
        int row = rowBase + ty * 4 + i;
        float as_p = acc[i][0] * aS[head * 8 + coff]     + acc[i][1] * aS[head * 8 + coff + 1]
                   + acc[i][2] * aS[head * 8 + coff + 2] + acc[i][3] * aS[head * 8 + coff + 3];
        float ad_p = acc[i][0] * aD[head * 8 + coff]     + acc[i][1] * aD[head * 8 + coff + 1]
                   + acc[i][2] * aD[head * 8 + coff + 2] + acc[i][3] * aD[head * 8 + coff + 3];
        as_p += __shfl_xor(as_p, 1);
        ad_p += __shfl_xor(ad_p, 1);
        if (row < GN) {
            ushort4 fv = make_ushort4(f2h(acc[i][0]), f2h(acc[i][1]), f2h(acc[i][2]), f2h(acc[i][3]));
            *(ushort4*)(h1f + (size_t)row * 64 + tx * 4) = fv;
            if ((tx & 1) == 0) {
                l1[(size_t)row * 8 + head] = f2h(as_p);
                ad1[row * 8 + head] = ad_p;
            }
        }
    }
}

// ------- layer-1 gather: one wave/dst; scalarized CSR walk ------------------
__global__ __launch_bounds__(256) void k_layer1(const int* __restrict__ rowptr,
                                                const int* __restrict__ deg,
                                                const int* __restrict__ csr,
                                                const unsigned short* __restrict__ h1f,
                                                const unsigned short* __restrict__ l1,
                                                const float* __restrict__ ad1,
                                                unsigned short* __restrict__ out1h) {
    // d is wave-uniform; readfirstlane pins it (and everything derived) to SGPRs
    int d = __builtin_amdgcn_readfirstlane(blockIdx.x * 4 + (threadIdx.x >> 6));
    int tt = threadIdx.x & 63;          // h*8+c
    int h = tt >> 3;
    int start = rowptr[d];              // s_load
    int dg = deg[d];                    // s_load
    float ad = ad1[d * 8 + h];
    float den = 0.f, acc = 0.f;
    int j = 0;
    for (; j + 4 <= dg; j += 4) {       // 4 outstanding 1-line gathers
        int s0 = csr[start + j];        // s_load_dwordx4
        int s1 = csr[start + j + 1];
        int s2 = csr[start + j + 2];
        int s3 = csr[start + j + 3];
        float w0 = __expf(lrelu(h2f(l1[(size_t)s0 * 8 + h]) + ad));
        float w1 = __expf(lrelu(h2f(l1[(size_t)s1 * 8 + h]) + ad));
        float w2 = __expf(lrelu(h2f(l1[(size_t)s2 * 8 + h]) + ad));
        float w3 = __expf(lrelu(h2f(l1[(size_t)s3 * 8 + h]) + ad));
        float g0 = h2f(h1f[(size_t)s0 * 64 + tt]);
        float g1 = h2f(h1f[(size_t)s1 * 64 + tt]);
        float g2 = h2f(h1f[(size_t)s2 * 64 + tt]);
        float g3 = h2f(h1f[(size_t)s3 * 64 + tt]);
        den += (w0 + w1) + (w2 + w3);
        acc += w0 * g0 + w1 * g1 + w2 * g2 + w3 * g3;
    }
    for (; j < dg; ++j) {
        int s0 = csr[start + j];
        float w0 = __expf(lrelu(h2f(l1[(size_t)s0 * 8 + h]) + ad));
        den += w0;
        acc += w0 * h2f(h1f[(size_t)s0 * 64 + tt]);
    }
    out1h[(size_t)d * 64 + tt] = f2h(acc / (den + 1e-16f));
}

// --- GEMM2 + fused logits: h2f_[GN][16] fp16 (32B rows), l2[GN] fp16, ad2 f32
__global__ __launch_bounds__(256) void k_gemm2(const unsigned short* __restrict__ agg1,
                                               const float* __restrict__ b1,
                                               const float* __restrict__ W2,
                                               const float* __restrict__ a_src,
                                               const float* __restrict__ a_dst,
                                               unsigned short* __restrict__ h2f_,
                                               unsigned short* __restrict__ l2,
                                               float* __restrict__ ad2) {
    __shared__ float As[64][65];
    __shared__ float Bs[64][20];
    __shared__ float aS[16], aD[16];
    const int t = threadIdx.x;
    const int rowBase = blockIdx.x * 64;

    {
        int k = t >> 2, c = (t & 3) << 2;
        float4 w = ((const float4*)W2)[t];
        Bs[k][c] = w.x; Bs[k][c + 1] = w.y; Bs[k][c + 2] = w.z; Bs[k][c + 3] = w.w;
    }
    if (t < 16) { aS[t] = a_src[t]; aD[t] = a_dst[t]; }
    const ushort4* a4p = (const ushort4*)agg1;
    const float4* b14 = (const float4*)b1;
#pragma unroll
    for (int i = 0; i < 4; ++i) {
        int v = t + i * 256;
        int r = v >> 4;
        int kq = v & 15;
        int row = rowBase + r;
        float ax = 0.f, ay = 0.f, az = 0.f, aw = 0.f;
        if (row < GN) {
            ushort4 a = a4p[row * 16 + kq];
            float4 bb = b14[kq];
            ax = fmaxf(h2f(a.x) + bb.x, 0.f);
            ay = fmaxf(h2f(a.y) + bb.y, 0.f);
            az = fmaxf(h2f(a.z) + bb.z, 0.f);
            aw = fmaxf(h2f(a.w) + bb.w, 0.f);
        }
        int kk = kq << 2;
        As[kk][r] = ax; As[kk + 1][r] = ay; As[kk + 2][r] = az; As[kk + 3][r] = aw;
    }
    __syncthreads();
    const int r = t >> 2;
    const int cg = (t & 3) << 2;
    float acc0 = 0.f, acc1 = 0.f, acc2 = 0.f, acc3 = 0.f;
#pragma unroll 8
    for (int k = 0; k < 64; ++k) {
        float a = As[k][r];
        float4 b = *(const float4*)&Bs[k][cg];
        acc0 += a * b.x; acc1 += a * b.y; acc2 += a * b.z; acc3 += a * b.w;
    }
    float as_p = acc0 * aS[cg] + acc1 * aS[cg + 1] + acc2 * aS[cg + 2] + acc3 * aS[cg + 3];
    float ad_p = acc0 * aD[cg] + acc1 * aD[cg + 1] + acc2 * aD[cg + 2] + acc3 * aD[cg + 3];
    as_p += __shfl_xor(as_p, 1); as_p += __shfl_xor(as_p, 2);
    ad_p += __shfl_xor(ad_p, 1); ad_p += __shfl_xor(ad_p, 2);
    int row = rowBase + r;
    if (row < GN) {
        ushort4 fv = make_ushort4(f2h(acc0), f2h(acc1), f2h(acc2), f2h(acc3));
        *(ushort4*)(h2f_ + (size_t)row * 16 + cg) = fv;
        if ((t & 3) == 0) {
            l2[row] = f2h(as_p);
            ad2[row] = ad_p;
        }
    }
}

// ------- layer-2 gather: one wave/dst, 16 ch x 4 edge-slots -----------------
__global__ __launch_bounds__(256) void k_layer2(const int* __restrict__ rowptr,
                                                const int* __restrict__ deg,
                                                const int* __restrict__ csr,
                                                const unsigned short* __restrict__ h2f_,
                                                const unsigned short* __restrict__ l2,
                                                const float* __restrict__ ad2,
                                                float* __restrict__ out2) {
    int d = __builtin_amdgcn_readfirstlane(blockIdx.x * 4 + (threadIdx.x >> 6));
    int tt = threadIdx.x & 63;
    int c = tt & 15;
    int sub = tt >> 4;
    int start = rowptr[d];
    int dg = deg[d];
    float ad = ad2[d];
    float den = 0.f, acc = 0.f;
    for (int base = 0; base < dg; base += 4) {
        int j = base + sub;
        bool val = j < dg;
        int s = csr[start + (val ? j : 0)];   // deg>=1 (self-loop) -> always valid
        float w = val ? __expf(lrelu(h2f(l2[s]) + ad)) : 0.f;
        float g = h2f(h2f_[(size_t)s * 16 + c]);
        den += w;
        acc += w * g;
    }
    acc += __shfl_xor(acc, 16); acc += __shfl_xor(acc, 32);
    den += __shfl_xor(den, 16); den += __shfl_xor(den, 32);
    if (sub == 0) out2[(size_t)d * 16 + c] = acc / (den + 1e-16f);
}

// -------- final: out[n,2] = concat_g(out2[g,n,:]+b2) @ Wf + bf --------------
__global__ __launch_bounds__(256) void k_final(const float* __restrict__ agg2,
                                               const float* __restrict__ b2,
                                               const float* __restrict__ Wf,
                                               const float* __restrict__ bf,
                                               float* __restrict__ out) {
    int n = blockIdx.x * 256 + threadIdx.x;
    if (n >= N_NODES) return;
    float o0 = bf[0], o1 = bf[1];
#pragma unroll
    for (int g = 0; g < G; ++g) {
        const float4* v4 = (const float4*)agg2 + (size_t)(g * N_NODES + n) * 4;
#pragma unroll
        for (int q = 0; q < 4; ++q) {
            float4 v = v4[q];
            float4 b = ((const float4*)b2)[q];
            v.x += b.x; v.y += b.y; v.z += b.z; v.w += b.w;
            int kb = g * 16 + q * 4;
            o0 += v.x * Wf[(kb + 0) * 2]     + v.y * Wf[(kb + 1) * 2]
                + v.z * Wf[(kb + 2) * 2]     + v.w * Wf[(kb + 3) * 2];
            o1 += v.x * Wf[(kb + 0) * 2 + 1] + v.y * Wf[(kb + 1) * 2 + 1]
                + v.z * Wf[(kb + 2) * 2 + 1] + v.w * Wf[(kb + 3) * 2 + 1];
        }
    }
    out[n * 2]     = o0;
    out[n * 2 + 1] = o1;
}

extern "C" void kernel_launch(void* const* d_in, const int* in_sizes, int n_in,
                              void* d_out, int out_size, void* d_ws, size_t ws_size,
                              hipStream_t stream) {
    const float* x      = (const float*)d_in[0];
    const int*   ei     = (const int*)d_in[1];
    const float* W1     = (const float*)d_in[2];
    const float* a_src1 = (const float*)d_in[3];
    const float* a_dst1 = (const float*)d_in[4];
    const float* b1     = (const float*)d_in[5];
    const float* W2     = (const float*)d_in[6];
    const float* a_src2 = (const float*)d_in[7];
    const float* a_dst2 = (const float*)d_in[8];
    const float* b2     = (const float*)d_in[9];
    const float* Wf     = (const float*)d_in[10];
    const float* bf     = (const float*)d_in[11];
    float* out = (float*)d_out;

    // workspace layout (lifetime aliasing):
    //   region A (36 MB): h1f[GN*64 u16] + l1[GN*8 u16]   (gemm1 -> layer1)
    //                     -> h2f_[GN*16 u16] + l2[GN u16] + out2[GN*16 f32]
    //   region B (32 MB): out1h[GN*64 u16]                (layer1 -> gemm2)
    //   region C (8 MB):  ad1[GN*8 f32] -> ad2[GN f32]
    //   ints: rowptr, deg, base_g, T, H, tmp, csr
    unsigned short* h1f = (unsigned short*)d_ws;             // GN*64 u16 (128B rows)
    unsigned short* l1  = h1f + (size_t)GN * 64;             // GN*8 u16
    unsigned short* h2f_ = h1f;                              // GN*16 u16 (alias)
    unsigned short* l2   = h2f_ + (size_t)GN * 16;           // GN u16 (alias)
    float* out2 = (float*)(l2 + GN);                         // GN*16 f32 (alias)
    unsigned short* out1h = h1f + (size_t)GN * 72;           // GN*64 u16
    float* ad1  = (float*)(out1h + (size_t)GN * 64);         // GN*8 f32
    float* ad2  = ad1;                                       // GN (alias)
    int*   iws    = (int*)(ad1 + (size_t)GN * 8);
    int*   rowptr = iws;                                     // GN
    int*   deg    = rowptr + GN;                             // GN
    int*   base_g = deg + GN;                                // NBUK+1
    int*   T      = base_g + (NBUK + 1);                     // NBUK
    int*   H      = T + NBUK;                                // NBLK_E*NBUK
    int*   tmp    = H + (size_t)NBLK_E * NBUK;               // GE
    int*   csr    = tmp + GE;                                // GE

    // CSR build via bucket sort (no global atomics, coalesced writes)
    k_hist   <<<NBLK_E, 256, 0, stream>>>(ei, H);
    k_scanH  <<<NBUK,   256, 0, stream>>>(H, T);
    k_scanT  <<<1,      256, 0, stream>>>(T, base_g);
    k_scatter<<<NBLK_E, 256, 0, stream>>>(ei, H, base_g, tmp);
    k_build  <<<NBUK,   256, 0, stream>>>(base_g, tmp, rowptr, deg, csr);

    k_gemm1  <<<(GN + 63) / 64, 256, 0, stream>>>(x, W1, a_src1, a_dst1, h1f, l1, ad1);
    k_layer1 <<<GN / 4, 256, 0, stream>>>(rowptr, deg, csr, h1f, l1, ad1, out1h);
    k_gemm2  <<<(GN + 63) / 64, 256, 0, stream>>>(out1h, b1, W2, a_src2, a_dst2, h2f_, l2, ad2);
    k_layer2 <<<GN / 4, 256, 0, stream>>>(rowptr, deg, csr, h2f_, l2, ad2, out2);
    k_final  <<<(N_NODES + 255) / 256, 256, 0, stream>>>(out2, b2, Wf, bf, out);
}